// Round 14
// baseline (773.973 us; speedup 1.0000x reference)
//
#include <hip/hip_runtime.h>
#include <hip/hip_bf16.h>
#include <math.h>

// Problem constants (fixed by the reference)
#define NB   64     // batch
#define CIN  64     // input channels
#define DIMD 128    // q/k/e channels
#define TT   120    // time
#define VV   25     // joints
#define HH   8      // heads
#define DHD  16     // DIM/H
#define WW   3      // temporal window
#define UU   75     // W*V
#define TC   24     // t-chunk in attention kernel (120 = 5*24)
#define TCO  4      // t-chunk in output kernel (120 = 4*30)

typedef __hip_bfloat16 bf16;
typedef float        f32x4  __attribute__((ext_vector_type(4)));
typedef unsigned int u32x4  __attribute__((ext_vector_type(4)));
typedef unsigned int u32x2  __attribute__((ext_vector_type(2)));
typedef __bf16       bf16x8 __attribute__((ext_vector_type(8)));

__device__ __forceinline__ float b2f(bf16 v)  { return __bfloat162float(v); }
__device__ __forceinline__ bf16  f2b(float v) { return __float2bfloat16(v); }

__device__ __forceinline__ unsigned short f2bu(float f) {
  unsigned u = __builtin_bit_cast(unsigned, f);
  return (unsigned short)((u + 0x7fffu + ((u >> 16) & 1u)) >> 16);  // RNE
}
__device__ __forceinline__ float bfu(unsigned short s) {
  unsigned u = ((unsigned)s) << 16;
  return __builtin_bit_cast(float, u);
}
__device__ __forceinline__ unsigned pack2(float a, float b) {
  return ((unsigned)f2bu(b) << 16) | (unsigned)f2bu(a);
}

// BUILTIN MFMA (R11 lesson: asm-wrapped MFMA is invisible to the GCN hazard
// recognizer -> missing MFMA->VALU wait-states -> silent corruption).
__device__ __forceinline__ f32x4 mfma_bf16(u32x4 a, u32x4 b, f32x4 d) {
  return __builtin_amdgcn_mfma_f32_16x16x32_bf16(
      __builtin_bit_cast(bf16x8, a), __builtin_bit_cast(bf16x8, b), d, 0, 0, 0);
}

// ---------------------------------------------------------------------------
// Fused A+B v6: weight-LDS round-trip removed. A-frags packed in-register
// directly from global f32 weights (row d = wid*32+mt*16+m16, 8 consecutive
// cols) with scale folded. No barriers between the three GEMMs.
// ---------------------------------------------------------------------------
__global__ __launch_bounds__(256, 3) void k_qke_mfma6(
    const float* __restrict__ x,
    const float* __restrict__ Wq, const float* __restrict__ bq,
    const float* __restrict__ Wk, const float* __restrict__ bk,
    const float* __restrict__ We, const float* __restrict__ be,
    const float* __restrict__ G,  const float* __restrict__ beta,
    const float* __restrict__ se_pe, const int* __restrict__ dis,
    bf16* __restrict__ qy, bf16* __restrict__ kkp)
{
  const int n = blockIdx.x / 30, t0 = (blockIdx.x % 30) * 4;
  __shared__ alignas(16) char uA[26624];                 // xl | yTG
  __shared__ alignas(16) unsigned short yT[112][64];     // [tv][c] swz
  __shared__ alignas(16) float spl[5][64];
  __shared__ alignas(16) int   dml[25][25];
  __shared__ alignas(16) float Gl[25][26];
  __shared__ alignas(16) float gsum[32];
  __shared__ alignas(16) float biasb[384];               // bq|bk|be

  float* xl  = (float*)uA;                               // [4][64][26] f32
  char*  yTG = uA;                                       // [112] x 128B swz
  #define XL(t, c, v) xl[(((t) * 64 + (c)) * 26) + (v)]

  const int tid = threadIdx.x;
  {
    const float* xb = x + (size_t)n * 192000 + t0 * 25;  // x[n][c][t0+t][v]
    for (int i = tid; i < 6400; i += 256) {
      const int c = i / 100, j = i % 100, t = j / 25, v = j % 25;
      XL(t, c, v) = xb[c * 3000 + j];
    }
  }
  for (int i = tid; i < 320; i += 256) spl[i / 64][i % 64] = se_pe[i];
  for (int i = tid; i < 625; i += 256) dml[i / 25][i % 25] = dis[i];
  for (int i = tid; i < 625; i += 256) Gl[i / 25][i % 25] = G[i];
  if (tid < 25) {
    float s = 0.f;
    for (int u = 0; u < 25; ++u) s += G[u * 25 + tid];
    gsum[tid] = s;
  }
  for (int i = tid; i < 384; i += 256)
    biasb[i] = (i < 128) ? bq[i] : (i < 256 ? bk[i - 128] : be[i - 256]);
  for (int i = tid; i < 12 * 64; i += 256)               // yT junk rows -> 0
    yT[100 + (i >> 6)][i & 63] = 0;
  __syncthreads();

  const int lane = tid & 63, wid = tid >> 6;
  const int m16 = lane & 15, kg = lane >> 4;

  // A-frags directly from global W (f32 -> scaled bf16 pack, in-register)
  #define LOAD_WFRAGS(af, Wsrc, SC)                                            \
    _Pragma("unroll")                                                          \
    for (int mt = 0; mt < 2; ++mt) {                                           \
      const int d_ = wid * 32 + mt * 16 + m16;                                 \
      _Pragma("unroll")                                                        \
      for (int ks = 0; ks < 2; ++ks) {                                         \
        const float4 p0 = *(const float4*)((Wsrc) + d_ * 64 + ks * 32 + kg * 8);     \
        const float4 p1 = *(const float4*)((Wsrc) + d_ * 64 + ks * 32 + kg * 8 + 4); \
        u32x4 f;                                                               \
        f[0] = pack2(p0.x * (SC), p0.y * (SC));                                \
        f[1] = pack2(p0.z * (SC), p0.w * (SC));                                \
        f[2] = pack2(p1.x * (SC), p1.y * (SC));                                \
        f[3] = pack2(p1.z * (SC), p1.w * (SC));                                \
        af[mt][ks] = f;                                                        \
      }                                                                        \
    }

  // ---- phase 1: yT = x + pe + struct-enc ----
  for (int idx = tid; idx < 6400; idx += 256) {
    const int c = idx & 63, tv = idx >> 6;
    const int t = tv / 25, v = tv % 25;
    const float dv = expf(-(float)(c & ~1) * (logf(10000.0f) / 64.0f));
    float acc = XL(t, c, v) +
                ((c & 1) ? cosf((float)v * dv) : sinf((float)v * dv));
    #pragma unroll
    for (int u = 0; u < 25; ++u)
      acc = fmaf(XL(t, c, u), spl[dml[u][v]][c], acc);
    *(unsigned short*)((char*)yT + tv * 128 + ((c * 2) ^ ((tv & 7) << 4))) =
        f2bu(acc);
  }
  __syncthreads();   // yT ready; xl DEAD (uA becomes yTG)

  // ---- phase 1b: yTG = y @ G ----
  for (int i = tid; i < 12 * 64; i += 256)
    *(unsigned short*)(yTG + (100 + (i >> 6)) * 128 + ((i & 63) * 2)) = 0;
  for (int idx = tid; idx < 6400; idx += 256) {
    const int c = idx & 63, tv = idx >> 6;
    const int t = tv / 25, v = tv % 25;
    float acc = 0.f;
    #pragma unroll
    for (int u = 0; u < 25; ++u) {
      const int ru = t * 25 + u;
      const float yv = bfu(*(const unsigned short*)((const char*)yT + ru * 128 +
                            ((c * 2) ^ ((ru & 7) << 4))));
      acc = fmaf(yv, Gl[u][v], acc);
    }
    *(unsigned short*)(yTG + tv * 128 + ((c * 2) ^ ((tv & 7) << 4))) =
        f2bu(acc);
  }
  __syncthreads();   // yTG ready — LAST barrier; GEMMs are straight-line

  bf16* qyb = qy  + (size_t)n * 384000 + t0 * 25;
  bf16* kkb = kkp + (size_t)n * 384000 + t0 * 25;
  const float betav = beta[0];

  // ---- q-GEMM ----
  {
    u32x4 aq[2][2];
    LOAD_WFRAGS(aq, Wq, 1.0f);
    for (int nt = 0; nt < 7; ++nt) {
      const int tv = nt * 16 + m16;
      const u32x4 b0 = *(const u32x4*)((const char*)yT + tv * 128 +
                        (((kg * 8) * 2) ^ ((tv & 7) << 4)));
      const u32x4 b1 = *(const u32x4*)((const char*)yT + tv * 128 +
                        (((32 + kg * 8) * 2) ^ ((tv & 7) << 4)));
      #pragma unroll
      for (int mt = 0; mt < 2; ++mt) {
        f32x4 acc = (f32x4)0.f;
        acc = mfma_bf16(aq[mt][0], b0, acc);
        acc = mfma_bf16(aq[mt][1], b1, acc);
        if (tv < 100) {
          const int dr = wid * 32 + mt * 16 + kg * 4;
          #pragma unroll
          for (int i2 = 0; i2 < 4; ++i2)
            qyb[(size_t)(dr + i2) * 3000 + tv] = f2b(acc[i2] + biasb[dr + i2]);
        }
      }
    }
  }

  // ---- k-GEMM into persistent kacc ----
  f32x4 kacc[2][7];
  #pragma unroll
  for (int mt = 0; mt < 2; ++mt)
    #pragma unroll
    for (int nt = 0; nt < 7; ++nt) kacc[mt][nt] = (f32x4)0.f;
  {
    u32x4 ak[2][2];
    LOAD_WFRAGS(ak, Wk, 1.0f);
    for (int nt = 0; nt < 7; ++nt) {
      const int tv = nt * 16 + m16;
      const u32x4 b0 = *(const u32x4*)((const char*)yT + tv * 128 +
                        (((kg * 8) * 2) ^ ((tv & 7) << 4)));
      const u32x4 b1 = *(const u32x4*)((const char*)yT + tv * 128 +
                        (((32 + kg * 8) * 2) ^ ((tv & 7) << 4)));
      #pragma unroll
      for (int mt = 0; mt < 2; ++mt) {
        kacc[mt][nt] = mfma_bf16(ak[mt][0], b0, kacc[mt][nt]);
        kacc[mt][nt] = mfma_bf16(ak[mt][1], b1, kacc[mt][nt]);
      }
    }
  }

  // ---- e-GEMM (beta*We) on yTG, accumulate, store kk ----
  {
    u32x4 ae[2][2];
    LOAD_WFRAGS(ae, We, betav);
    for (int nt = 0; nt < 7; ++nt) {
      const int tv = nt * 16 + m16;
      const u32x4 b0 = *(const u32x4*)(yTG + tv * 128 +
                        (((kg * 8) * 2) ^ ((tv & 7) << 4)));
      const u32x4 b1 = *(const u32x4*)(yTG + tv * 128 +
                        (((32 + kg * 8) * 2) ^ ((tv & 7) << 4)));
      #pragma unroll
      for (int mt = 0; mt < 2; ++mt) {
        kacc[mt][nt] = mfma_bf16(ae[mt][0], b0, kacc[mt][nt]);
        kacc[mt][nt] = mfma_bf16(ae[mt][1], b1, kacc[mt][nt]);
        if (tv < 100) {
          const int vv = tv % 25;
          const int dr = wid * 32 + mt * 16 + kg * 4;
          #pragma unroll
          for (int i2 = 0; i2 < 4; ++i2)
            kkb[(size_t)(dr + i2) * 3000 + tv] =
                f2b(kacc[mt][nt][i2] + biasb[128 + dr + i2] +
                    betav * biasb[256 + dr + i2] * gsum[vv]);
        }
      }
    }
  }
  #undef LOAD_WFRAGS
  #undef XL
}

// ---------------------------------------------------------------------------
// Kernel C (R13-verbatim): writes PADDED attP[n][h][32][104]
// ---------------------------------------------------------------------------
__global__ __launch_bounds__(256) void k_att(
    const bf16* __restrict__ qy, const bf16* __restrict__ kkp,
    const float* __restrict__ bq, const float* __restrict__ disg,
    const float* __restrict__ att0, const float* __restrict__ alpha,
    unsigned short* __restrict__ attP)
{
  const int n = blockIdx.x / HH, h = blockIdx.x % HH;
  __shared__ float qs[DHD][TC + 2][VV];
  __shared__ float ks[DHD][TC][VV];
  __shared__ float mxv[VV], smv[VV];
  const int tid = threadIdx.x;
  const int v = tid % VV;
  const int g = tid / VV;
  const bool act = (g < 10);
  int u_[8], w_[8], up_[8];
  #pragma unroll
  for (int j = 0; j < 8; ++j) {
    int u = g + 10 * j;
    u_[j] = u;
    if (u >= UU) u = 0;
    w_[j] = u / VV; up_[j] = u % VV;
  }
  float acc[8] = {0.f, 0.f, 0.f, 0.f, 0.f, 0.f, 0.f, 0.f};

  for (int t0 = 0; t0 < TT; t0 += TC) {
    __syncthreads();
    for (int i = tid; i < DHD * (TC + 2) * VV; i += 256) {
      const int dh = i / ((TC + 2) * VV);
      const int r  = i % ((TC + 2) * VV);
      const int tt = r / VV, vv = r % VV;
      const int tq = t0 + tt - 1;
      const int dd = h * DHD + dh;
      qs[dh][tt][vv] = (tq >= 0 && tq < TT)
          ? b2f(qy[((size_t)(n * DIMD + dd) * TT + tq) * VV + vv]) : bq[dd];
    }
    for (int i = tid; i < DHD * TC * VV; i += 256) {
      const int dh = i / (TC * VV);
      const int r  = i % (TC * VV);
      const int tt = r / VV, vv = r % VV;
      ks[dh][tt][vv] =
          b2f(kkp[((size_t)(n * DIMD + h * DHD + dh) * TT + t0 + tt) * VV + vv]);
    }
    __syncthreads();
    if (act) {
      for (int dh = 0; dh < DHD; ++dh) {
        #pragma unroll 4
        for (int tt = 0; tt < TC; ++tt) {
          const float kv = ks[dh][tt][v];
          #pragma unroll
          for (int j = 0; j < 8; ++j)
            acc[j] = fmaf(qs[dh][tt + w_[j]][up_[j]], kv, acc[j]);
        }
      }
    }
  }
  __syncthreads();
  float* att_s = &qs[0][0][0];
  const float inv = 1.0f / (float)(DHD * TT);
  if (act) {
    #pragma unroll
    for (int j = 0; j < 8; ++j) {
      if (u_[j] < UU) {
        const bool m = disg[(h * VV + up_[j]) * VV + v] > 0.f;
        att_s[u_[j] * VV + v] = m ? acc[j] * inv : -9e15f;
      }
    }
  }
  __syncthreads();
  if (tid < VV) {
    float mx = -INFINITY;
    for (int u = 0; u < UU; ++u) mx = fmaxf(mx, att_s[u * VV + tid]);
    float sm = 0.f;
    for (int u = 0; u < UU; ++u) sm += expf(att_s[u * VV + tid] - mx);
    mxv[tid] = mx; smv[tid] = sm;
  }
  __syncthreads();
  const float al = alpha[0];
  unsigned* dst = (unsigned*)(attP + ((size_t)(n * HH + h) * 32) * 104);
  for (int i = tid; i < 1664; i += 256) {     // 32 x 52 u32 (= 104 u16)
    const int vc = i / 52, u0 = (i % 52) * 2;
    unsigned val = 0u;
    if (vc < VV) {
      float f0 = 0.f, f1 = 0.f;
      if (u0 < UU)
        f0 = expf(att_s[u0 * VV + vc] - mxv[vc]) / smv[vc] * al
             + att0[(h * VV + u0 % VV) * VV + vc];
      if (u0 + 1 < UU)
        f1 = expf(att_s[(u0 + 1) * VV + vc] - mxv[vc]) / smv[vc] * al
             + att0[(h * VV + (u0 + 1) % VV) * VV + vc];
      val = pack2(f0, f1);
    }
    dst[i] = val;
  }
}

// ---------------------------------------------------------------------------
// Kernel D v5: wol deleted — stage2 A-frags direct from global Wo/Wd with
// BN scale folded per fragment row. LDS = xsl2 dbuf (28.7K, aliased with
// prologue xu2) + attB (13.3K) = 42K -> 3 blocks/CU.
// ---------------------------------------------------------------------------
__global__ __launch_bounds__(256, 3) void k_out_mfma5(
    const float* __restrict__ x, const unsigned short* __restrict__ attP,
    const float* __restrict__ Wo, const float* __restrict__ b_o,
    const float* __restrict__ g_o, const float* __restrict__ be_o,
    const float* __restrict__ m_o, const float* __restrict__ v_o,
    const float* __restrict__ Wd, const float* __restrict__ b_d,
    const float* __restrict__ g_d, const float* __restrict__ be_d,
    const float* __restrict__ m_d, const float* __restrict__ v_d,
    float* __restrict__ out)
{
  const int n = blockIdx.x / 30, t0 = (blockIdx.x % 30) * TCO;
  __shared__ alignas(16) char uB[28672];                   // xu2 | xsl2[2]
  __shared__ alignas(16) unsigned short attB[2][32][104];  // 13,312 B dbuf
  unsigned short* xu2 = (unsigned short*)uB;               // [(tr*64+c)*104+u]
  const int tid = threadIdx.x;
  const int lane = tid & 63, wid = tid >> 6;
  const int m16 = lane & 15, kg = lane >> 4;

  #define XSLB(b) (uB + (b) * 14336)            // [112] rows x 128B swz

  #define STAGE_XU(tb)                                                         \
    for (int i = tid; i < 2 * 64 * 48; i += 256) {                             \
      const int u0 = (i % 48) * 2, c = (i / 48) & 63, tr = i / (48 * 64);      \
      float f0 = 0.f, f1 = 0.f;                                                \
      if (u0 < UU) {                                                           \
        const int w = u0 / VV, up = u0 % VV, ts = t0 + (tb) + tr + w - 1;      \
        if (ts >= 0 && ts < TT) f0 = x[((n * 64 + c) * TT + ts) * VV + up];    \
      }                                                                        \
      if (u0 + 1 < UU) {                                                       \
        const int u = u0 + 1, w = u / VV, up = u % VV;                         \
        const int ts = t0 + (tb) + tr + w - 1;                                 \
        if (ts >= 0 && ts < TT) f1 = x[((n * 64 + c) * TT + ts) * VV + up];    \
      }                                                                        \
      *(unsigned*)(xu2 + (tr * 64 + c) * 104 + u0) = pack2(f0, f1);            \
    }

  #define STAGE_ATT(hh, buf)                                                   \
    {                                                                          \
      const u32x4* srcv =                                                      \
          (const u32x4*)(attP + ((size_t)(n * HH + (hh)) * 32) * 104);         \
      u32x4* dstv = (u32x4*)&attB[buf][0][0];                                  \
      for (int i = tid; i < 416; i += 256) dstv[i] = srcv[i];                  \
    }

  // ---- prologue: A-frags from xu2 in two 2-t chunks ----
  STAGE_XU(0);
  __syncthreads();
  u32x4 af[4][3];
  if (wid < 2) {
    #pragma unroll
    for (int mt = 0; mt < 4; ++mt)
      #pragma unroll
      for (int ks = 0; ks < 3; ++ks)
        af[mt][ks] = *(const u32x4*)(xu2 + (wid * 64 + mt * 16 + m16) * 104 +
                                     ks * 32 + kg * 8);
  }
  __syncthreads();   // chunk-1 reads drained before overwrite
  STAGE_XU(2);
  STAGE_ATT(0, 0);
  __syncthreads();
  if (wid >= 2) {
    #pragma unroll
    for (int mt = 0; mt < 4; ++mt)
      #pragma unroll
      for (int ks = 0; ks < 3; ++ks)
        af[mt][ks] = *(const u32x4*)(xu2 + ((wid - 2) * 64 + mt * 16 + m16) * 104 +
                                     ks * 32 + kg * 8);
  }
  __syncthreads();   // FENCE: all xu2 reads drained; uB becomes xsl2
  // zero junk rows (tv 100..111) of BOTH xsl buffers (never rewritten)
  for (int i = tid; i < 2 * 12 * 64; i += 256) {
    const int b = i / (12 * 64), r = i % (12 * 64);
    *(unsigned short*)(XSLB(b) + (100 + (r >> 6)) * 128 + ((r & 63) * 2)) = 0;
  }

  // per-thread BN scales for this thread's two A-frag rows (d = wid*32+mt*16+m16)
  float so_m[2], sd_m[2];
  #pragma unroll
  for (int mt = 0; mt < 2; ++mt) {
    const int d = wid * 32 + mt * 16 + m16;
    so_m[mt] = g_o[d] * rsqrtf(v_o[d] + 1e-5f);
    sd_m[mt] = g_d[d] * rsqrtf(v_d[d] + 1e-5f);
  }

  f32x4 acc2[2][7];
  #pragma unroll
  for (int mt = 0; mt < 2; ++mt)
    #pragma unroll
    for (int nt = 0; nt < 7; ++nt) acc2[mt][nt] = (f32x4)0.f;

  for (int h = 0; h <= HH; ++h) {
    const int pb = h & 1;
    char* xs = XSLB(pb);
    // stage2 A-frags direct from global (issued early; latency hides under
    // stage1 MFMAs). Layout identical to the old wol path.
    u32x4 a2[2][2];
    #pragma unroll
    for (int mt = 0; mt < 2; ++mt) {
      const int d = wid * 32 + mt * 16 + m16;
      const float sc = (h < HH) ? so_m[mt] : sd_m[mt];
      const float* wr = (h < HH) ? (Wo + (size_t)d * 512 + h * 64)
                                 : (Wd + (size_t)d * 64);
      #pragma unroll
      for (int ks = 0; ks < 2; ++ks) {
        const float4 p0 = *(const float4*)(wr + ks * 32 + kg * 8);
        const float4 p1 = *(const float4*)(wr + ks * 32 + kg * 8 + 4);
        u32x4 f;
        f[0] = pack2(p0.x * sc, p0.y * sc); f[1] = pack2(p0.z * sc, p0.w * sc);
        f[2] = pack2(p1.x * sc, p1.y * sc); f[3] = pack2(p1.z * sc, p1.w * sc);
        a2[mt][ks] = f;
      }
    }
    if (h + 1 < HH) { STAGE_ATT(h + 1, (h + 1) & 1); }
    f32x4 a1[4][2];
    if (h < HH) {
      u32x4 bfr[2][3];
      #pragma unroll
      for (int nt = 0; nt < 2; ++nt)
        #pragma unroll
        for (int ks = 0; ks < 3; ++ks)
          bfr[nt][ks] =
              *(const u32x4*)&attB[pb][nt * 16 + m16][ks * 32 + kg * 8];
      #pragma unroll
      for (int mt = 0; mt < 4; ++mt)
        #pragma unroll
        for (int nt = 0; nt < 2; ++nt) {
          a1[mt][nt] = (f32x4)0.f;
          #pragma unroll
          for (int ks = 0; ks < 3; ++ks)
            a1[mt][nt] = mfma_bf16(af[mt][ks], bfr[nt][ks], a1[mt][nt]);
        }
    }
    // write this h's xs buffer (parity pb; h-1 used 1-pb -> no hazard)
    if (h < HH) {
      #pragma unroll
      for (int mt = 0; mt < 4; ++mt)
        #pragma unroll
        for (int nt = 0; nt < 2; ++nt) {
          const int v = nt * 16 + m16;
          if (v < VV) {
            const int tv = wid * VV + v;
            const int c0 = mt * 16 + kg * 4;
            u32x2 pk;
            pk[0] = pack2(a1[mt][nt][0], a1[mt][nt][1]);
            pk[1] = pack2(a1[mt][nt][2], a1[mt][nt][3]);
            char* p = xs + tv * 128 + ((c0 * 2) ^ ((tv & 7) << 4));
            *(u32x2*)p = pk;
          }
        }
    } else {
      for (int i = tid; i < 6400; i += 256) {
        const int c = i / 100, j = i % 100;
        const float f = x[((size_t)(n * 64 + c) * TT + t0) * VV + j];
        *(unsigned short*)(xs + j * 128 + ((c * 2) ^ ((j & 7) << 4))) =
            f2bu(f);
      }
    }
    __syncthreads();   // single barrier: xs writes(pb) -> reads(pb)
    #pragma unroll
    for (int nt = 0; nt < 7; ++nt) {
      const int tv = nt * 16 + m16;
      const u32x4 b0 = *(const u32x4*)(xs + tv * 128 +
                        (((kg * 8) * 2) ^ ((tv & 7) << 4)));
      const u32x4 b1 = *(const u32x4*)(xs + tv * 128 +
                        (((32 + kg * 8) * 2) ^ ((tv & 7) << 4)));
      #pragma unroll
      for (int mt = 0; mt < 2; ++mt) {
        acc2[mt][nt] = mfma_bf16(a2[mt][0], b0, acc2[mt][nt]);
        acc2[mt][nt] = mfma_bf16(a2[mt][1], b1, acc2[mt][nt]);
      }
    }
  }

  #pragma unroll
  for (int mt = 0; mt < 2; ++mt) {
    float cc[4];
    #pragma unroll
    for (int i = 0; i < 4; ++i) {
      const int d = wid * 32 + mt * 16 + kg * 4 + i;
      const float so2 = g_o[d] * rsqrtf(v_o[d] + 1e-5f);
      const float sd2 = g_d[d] * rsqrtf(v_d[d] + 1e-5f);
      cc[i] = b_o[d] * so2 + be_o[d] - m_o[d] * so2
            + b_d[d] * sd2 + be_d[d] - m_d[d] * sd2;
    }
    #pragma unroll
    for (int nt = 0; nt < 7; ++nt) {
      const int tv = nt * 16 + m16;
      if (tv < 100) {
        const int t = t0 + tv / VV, v = tv % VV;
        #pragma unroll
        for (int i = 0; i < 4; ++i) {
          const int d = wid * 32 + mt * 16 + kg * 4 + i;
          const float z = acc2[mt][nt][i] + cc[i];
          out[((n * DIMD + d) * TT + t) * VV + v] = (z >= 0.f) ? z : 0.1f * z;
        }
      }
    }
  }
  #undef STAGE_XU
  #undef STAGE_ATT
  #undef XSLB
}

// ---------------------------------------------------------------------------
extern "C" void kernel_launch(void* const* d_in, const int* in_sizes, int n_in,
                              void* d_out, int out_size, void* d_ws, size_t ws_size,
                              hipStream_t stream)
{
  (void)in_sizes; (void)n_in; (void)out_size; (void)ws_size;
  const float* x     = (const float*)d_in[0];
  const float* Wq    = (const float*)d_in[1];
  const float* bq    = (const float*)d_in[2];
  const float* Wk    = (const float*)d_in[3];
  const float* bk    = (const float*)d_in[4];
  const float* We    = (const float*)d_in[5];
  const float* be    = (const float*)d_in[6];
  const float* G     = (const float*)d_in[7];
  const float* sepe  = (const float*)d_in[8];
  const float* att0  = (const float*)d_in[9];
  const float* alpha = (const float*)d_in[10];
  const float* beta  = (const float*)d_in[11];
  const float* Wo    = (const float*)d_in[12];
  const float* b_o   = (const float*)d_in[13];
  const float* g_o   = (const float*)d_in[14];
  const float* be_o  = (const float*)d_in[15];
  const float* m_o   = (const float*)d_in[16];
  const float* v_o   = (const float*)d_in[17];
  const float* Wd    = (const float*)d_in[18];
  const float* b_d   = (const float*)d_in[19];
  const float* g_d   = (const float*)d_in[20];
  const float* be_d  = (const float*)d_in[21];
  const float* m_d   = (const float*)d_in[22];
  const float* v_d   = (const float*)d_in[23];
  const int*   dism  = (const int*)d_in[24];
  const float* disg  = (const float*)d_in[25];

  // Workspace: qy @0 (49.152 MB), kk @49,152,000, attP @98,304,000 (3.41 MB)
  char* ws = (char*)d_ws;
  bf16* qy   = (bf16*)(ws);
  bf16* kkp  = (bf16*)(ws + 49152000);
  unsigned short* attP = (unsigned short*)(ws + 98304000);

  k_qke_mfma6<<<NB * 30, 256, 0, stream>>>(x, Wq, bq, Wk, bk, We, be, G, beta,
                                           sepe, dism, qy, kkp);
  k_att<<<NB * HH, 256, 0, stream>>>(qy, kkp, bq, disg, att0, alpha, attP);
  k_out_mfma5<<<NB * 30, 256, 0, stream>>>(x, attP, Wo, b_o, g_o, be_o, m_o, v_o,
                                           Wd, b_d, g_d, be_d, m_d, v_d, (float*)d_out);
}

// Round 15
// 655.229 us; speedup vs baseline: 1.1812x; 1.1812x over previous
//
#include <hip/hip_runtime.h>
#include <hip/hip_bf16.h>
#include <math.h>

// Problem constants (fixed by the reference)
#define NB   64     // batch
#define CIN  64     // input channels
#define DIMD 128    // q/k/e channels
#define TT   120    // time
#define VV   25     // joints
#define HH   8      // heads
#define DHD  16     // DIM/H
#define WW   3      // temporal window
#define UU   75     // W*V
#define TC   24     // t-chunk in attention kernel (120 = 5*24)
#define TCO  4      // t-chunk in output kernel (120 = 4*30)

typedef __hip_bfloat16 bf16;
typedef float        f32x4  __attribute__((ext_vector_type(4)));
typedef unsigned int u32x4  __attribute__((ext_vector_type(4)));
typedef unsigned int u32x2  __attribute__((ext_vector_type(2)));
typedef __bf16       bf16x8 __attribute__((ext_vector_type(8)));

__device__ __forceinline__ float b2f(bf16 v)  { return __bfloat162float(v); }
__device__ __forceinline__ bf16  f2b(float v) { return __float2bfloat16(v); }

__device__ __forceinline__ unsigned short f2bu(float f) {
  unsigned u = __builtin_bit_cast(unsigned, f);
  return (unsigned short)((u + 0x7fffu + ((u >> 16) & 1u)) >> 16);  // RNE
}
__device__ __forceinline__ float bfu(unsigned short s) {
  unsigned u = ((unsigned)s) << 16;
  return __builtin_bit_cast(float, u);
}
__device__ __forceinline__ unsigned pack2(float a, float b) {
  return ((unsigned)f2bu(b) << 16) | (unsigned)f2bu(a);
}

// BUILTIN MFMA (R11 lesson: asm-wrapped MFMA is invisible to the GCN hazard
// recognizer -> missing MFMA->VALU wait-states -> silent corruption).
__device__ __forceinline__ f32x4 mfma_bf16(u32x4 a, u32x4 b, f32x4 d) {
  return __builtin_amdgcn_mfma_f32_16x16x32_bf16(
      __builtin_bit_cast(bf16x8, a), __builtin_bit_cast(bf16x8, b), d, 0, 0, 0);
}

// ---------------------------------------------------------------------------
// Fused A+B v6 (R14-verbatim, passing): A-frags direct from global weights;
// no barriers between the three GEMMs; xl aliased with yTG.
// ---------------------------------------------------------------------------
__global__ __launch_bounds__(256, 3) void k_qke_mfma6(
    const float* __restrict__ x,
    const float* __restrict__ Wq, const float* __restrict__ bq,
    const float* __restrict__ Wk, const float* __restrict__ bk,
    const float* __restrict__ We, const float* __restrict__ be,
    const float* __restrict__ G,  const float* __restrict__ beta,
    const float* __restrict__ se_pe, const int* __restrict__ dis,
    bf16* __restrict__ qy, bf16* __restrict__ kkp)
{
  const int n = blockIdx.x / 30, t0 = (blockIdx.x % 30) * 4;
  __shared__ alignas(16) char uA[26624];                 // xl | yTG
  __shared__ alignas(16) unsigned short yT[112][64];     // [tv][c] swz
  __shared__ alignas(16) float spl[5][64];
  __shared__ alignas(16) int   dml[25][25];
  __shared__ alignas(16) float Gl[25][26];
  __shared__ alignas(16) float gsum[32];
  __shared__ alignas(16) float biasb[384];               // bq|bk|be

  float* xl  = (float*)uA;                               // [4][64][26] f32
  char*  yTG = uA;                                       // [112] x 128B swz
  #define XL(t, c, v) xl[(((t) * 64 + (c)) * 26) + (v)]

  const int tid = threadIdx.x;
  {
    const float* xb = x + (size_t)n * 192000 + t0 * 25;  // x[n][c][t0+t][v]
    for (int i = tid; i < 6400; i += 256) {
      const int c = i / 100, j = i % 100, t = j / 25, v = j % 25;
      XL(t, c, v) = xb[c * 3000 + j];
    }
  }
  for (int i = tid; i < 320; i += 256) spl[i / 64][i % 64] = se_pe[i];
  for (int i = tid; i < 625; i += 256) dml[i / 25][i % 25] = dis[i];
  for (int i = tid; i < 625; i += 256) Gl[i / 25][i % 25] = G[i];
  if (tid < 25) {
    float s = 0.f;
    for (int u = 0; u < 25; ++u) s += G[u * 25 + tid];
    gsum[tid] = s;
  }
  for (int i = tid; i < 384; i += 256)
    biasb[i] = (i < 128) ? bq[i] : (i < 256 ? bk[i - 128] : be[i - 256]);
  for (int i = tid; i < 12 * 64; i += 256)               // yT junk rows -> 0
    yT[100 + (i >> 6)][i & 63] = 0;
  __syncthreads();

  const int lane = tid & 63, wid = tid >> 6;
  const int m16 = lane & 15, kg = lane >> 4;

  // A-frags directly from global W (f32 -> scaled bf16 pack, in-register)
  #define LOAD_WFRAGS(af, Wsrc, SC)                                            \
    _Pragma("unroll")                                                          \
    for (int mt = 0; mt < 2; ++mt) {                                           \
      const int d_ = wid * 32 + mt * 16 + m16;                                 \
      _Pragma("unroll")                                                        \
      for (int ks = 0; ks < 2; ++ks) {                                         \
        const float4 p0 = *(const float4*)((Wsrc) + d_ * 64 + ks * 32 + kg * 8);     \
        const float4 p1 = *(const float4*)((Wsrc) + d_ * 64 + ks * 32 + kg * 8 + 4); \
        u32x4 f;                                                               \
        f[0] = pack2(p0.x * (SC), p0.y * (SC));                                \
        f[1] = pack2(p0.z * (SC), p0.w * (SC));                                \
        f[2] = pack2(p1.x * (SC), p1.y * (SC));                                \
        f[3] = pack2(p1.z * (SC), p1.w * (SC));                                \
        af[mt][ks] = f;                                                        \
      }                                                                        \
    }

  // ---- phase 1: yT = x + pe + struct-enc ----
  for (int idx = tid; idx < 6400; idx += 256) {
    const int c = idx & 63, tv = idx >> 6;
    const int t = tv / 25, v = tv % 25;
    const float dv = expf(-(float)(c & ~1) * (logf(10000.0f) / 64.0f));
    float acc = XL(t, c, v) +
                ((c & 1) ? cosf((float)v * dv) : sinf((float)v * dv));
    #pragma unroll
    for (int u = 0; u < 25; ++u)
      acc = fmaf(XL(t, c, u), spl[dml[u][v]][c], acc);
    *(unsigned short*)((char*)yT + tv * 128 + ((c * 2) ^ ((tv & 7) << 4))) =
        f2bu(acc);
  }
  __syncthreads();   // yT ready; xl DEAD (uA becomes yTG)

  // ---- phase 1b: yTG = y @ G ----
  for (int i = tid; i < 12 * 64; i += 256)
    *(unsigned short*)(yTG + (100 + (i >> 6)) * 128 + ((i & 63) * 2)) = 0;
  for (int idx = tid; idx < 6400; idx += 256) {
    const int c = idx & 63, tv = idx >> 6;
    const int t = tv / 25, v = tv % 25;
    float acc = 0.f;
    #pragma unroll
    for (int u = 0; u < 25; ++u) {
      const int ru = t * 25 + u;
      const float yv = bfu(*(const unsigned short*)((const char*)yT + ru * 128 +
                            ((c * 2) ^ ((ru & 7) << 4))));
      acc = fmaf(yv, Gl[u][v], acc);
    }
    *(unsigned short*)(yTG + tv * 128 + ((c * 2) ^ ((tv & 7) << 4))) =
        f2bu(acc);
  }
  __syncthreads();   // yTG ready — LAST barrier; GEMMs are straight-line

  bf16* qyb = qy  + (size_t)n * 384000 + t0 * 25;
  bf16* kkb = kkp + (size_t)n * 384000 + t0 * 25;
  const float betav = beta[0];

  // ---- q-GEMM ----
  {
    u32x4 aq[2][2];
    LOAD_WFRAGS(aq, Wq, 1.0f);
    for (int nt = 0; nt < 7; ++nt) {
      const int tv = nt * 16 + m16;
      const u32x4 b0 = *(const u32x4*)((const char*)yT + tv * 128 +
                        (((kg * 8) * 2) ^ ((tv & 7) << 4)));
      const u32x4 b1 = *(const u32x4*)((const char*)yT + tv * 128 +
                        (((32 + kg * 8) * 2) ^ ((tv & 7) << 4)));
      #pragma unroll
      for (int mt = 0; mt < 2; ++mt) {
        f32x4 acc = (f32x4)0.f;
        acc = mfma_bf16(aq[mt][0], b0, acc);
        acc = mfma_bf16(aq[mt][1], b1, acc);
        if (tv < 100) {
          const int dr = wid * 32 + mt * 16 + kg * 4;
          #pragma unroll
          for (int i2 = 0; i2 < 4; ++i2)
            qyb[(size_t)(dr + i2) * 3000 + tv] = f2b(acc[i2] + biasb[dr + i2]);
        }
      }
    }
  }

  // ---- k-GEMM into persistent kacc ----
  f32x4 kacc[2][7];
  #pragma unroll
  for (int mt = 0; mt < 2; ++mt)
    #pragma unroll
    for (int nt = 0; nt < 7; ++nt) kacc[mt][nt] = (f32x4)0.f;
  {
    u32x4 ak[2][2];
    LOAD_WFRAGS(ak, Wk, 1.0f);
    for (int nt = 0; nt < 7; ++nt) {
      const int tv = nt * 16 + m16;
      const u32x4 b0 = *(const u32x4*)((const char*)yT + tv * 128 +
                        (((kg * 8) * 2) ^ ((tv & 7) << 4)));
      const u32x4 b1 = *(const u32x4*)((const char*)yT + tv * 128 +
                        (((32 + kg * 8) * 2) ^ ((tv & 7) << 4)));
      #pragma unroll
      for (int mt = 0; mt < 2; ++mt) {
        kacc[mt][nt] = mfma_bf16(ak[mt][0], b0, kacc[mt][nt]);
        kacc[mt][nt] = mfma_bf16(ak[mt][1], b1, kacc[mt][nt]);
      }
    }
  }

  // ---- e-GEMM (beta*We) on yTG, accumulate, store kk ----
  {
    u32x4 ae[2][2];
    LOAD_WFRAGS(ae, We, betav);
    for (int nt = 0; nt < 7; ++nt) {
      const int tv = nt * 16 + m16;
      const u32x4 b0 = *(const u32x4*)(yTG + tv * 128 +
                        (((kg * 8) * 2) ^ ((tv & 7) << 4)));
      const u32x4 b1 = *(const u32x4*)(yTG + tv * 128 +
                        (((32 + kg * 8) * 2) ^ ((tv & 7) << 4)));
      #pragma unroll
      for (int mt = 0; mt < 2; ++mt) {
        kacc[mt][nt] = mfma_bf16(ae[mt][0], b0, kacc[mt][nt]);
        kacc[mt][nt] = mfma_bf16(ae[mt][1], b1, kacc[mt][nt]);
        if (tv < 100) {
          const int vv = tv % 25;
          const int dr = wid * 32 + mt * 16 + kg * 4;
          #pragma unroll
          for (int i2 = 0; i2 < 4; ++i2)
            kkb[(size_t)(dr + i2) * 3000 + tv] =
                f2b(kacc[mt][nt][i2] + biasb[128 + dr + i2] +
                    betav * biasb[256 + dr + i2] * gsum[vv]);
        }
      }
    }
  }
  #undef LOAD_WFRAGS
  #undef XL
}

// ---------------------------------------------------------------------------
// Kernel C (R13-verbatim): writes PADDED attP[n][h][32][104]
// ---------------------------------------------------------------------------
__global__ __launch_bounds__(256) void k_att(
    const bf16* __restrict__ qy, const bf16* __restrict__ kkp,
    const float* __restrict__ bq, const float* __restrict__ disg,
    const float* __restrict__ att0, const float* __restrict__ alpha,
    unsigned short* __restrict__ attP)
{
  const int n = blockIdx.x / HH, h = blockIdx.x % HH;
  __shared__ float qs[DHD][TC + 2][VV];
  __shared__ float ks[DHD][TC][VV];
  __shared__ float mxv[VV], smv[VV];
  const int tid = threadIdx.x;
  const int v = tid % VV;
  const int g = tid / VV;
  const bool act = (g < 10);
  int u_[8], w_[8], up_[8];
  #pragma unroll
  for (int j = 0; j < 8; ++j) {
    int u = g + 10 * j;
    u_[j] = u;
    if (u >= UU) u = 0;
    w_[j] = u / VV; up_[j] = u % VV;
  }
  float acc[8] = {0.f, 0.f, 0.f, 0.f, 0.f, 0.f, 0.f, 0.f};

  for (int t0 = 0; t0 < TT; t0 += TC) {
    __syncthreads();
    for (int i = tid; i < DHD * (TC + 2) * VV; i += 256) {
      const int dh = i / ((TC + 2) * VV);
      const int r  = i % ((TC + 2) * VV);
      const int tt = r / VV, vv = r % VV;
      const int tq = t0 + tt - 1;
      const int dd = h * DHD + dh;
      qs[dh][tt][vv] = (tq >= 0 && tq < TT)
          ? b2f(qy[((size_t)(n * DIMD + dd) * TT + tq) * VV + vv]) : bq[dd];
    }
    for (int i = tid; i < DHD * TC * VV; i += 256) {
      const int dh = i / (TC * VV);
      const int r  = i % (TC * VV);
      const int tt = r / VV, vv = r % VV;
      ks[dh][tt][vv] =
          b2f(kkp[((size_t)(n * DIMD + h * DHD + dh) * TT + t0 + tt) * VV + vv]);
    }
    __syncthreads();
    if (act) {
      for (int dh = 0; dh < DHD; ++dh) {
        #pragma unroll 4
        for (int tt = 0; tt < TC; ++tt) {
          const float kv = ks[dh][tt][v];
          #pragma unroll
          for (int j = 0; j < 8; ++j)
            acc[j] = fmaf(qs[dh][tt + w_[j]][up_[j]], kv, acc[j]);
        }
      }
    }
  }
  __syncthreads();
  float* att_s = &qs[0][0][0];
  const float inv = 1.0f / (float)(DHD * TT);
  if (act) {
    #pragma unroll
    for (int j = 0; j < 8; ++j) {
      if (u_[j] < UU) {
        const bool m = disg[(h * VV + up_[j]) * VV + v] > 0.f;
        att_s[u_[j] * VV + v] = m ? acc[j] * inv : -9e15f;
      }
    }
  }
  __syncthreads();
  if (tid < VV) {
    float mx = -INFINITY;
    for (int u = 0; u < UU; ++u) mx = fmaxf(mx, att_s[u * VV + tid]);
    float sm = 0.f;
    for (int u = 0; u < UU; ++u) sm += expf(att_s[u * VV + tid] - mx);
    mxv[tid] = mx; smv[tid] = sm;
  }
  __syncthreads();
  const float al = alpha[0];
  unsigned* dst = (unsigned*)(attP + ((size_t)(n * HH + h) * 32) * 104);
  for (int i = tid; i < 1664; i += 256) {     // 32 x 52 u32 (= 104 u16)
    const int vc = i / 52, u0 = (i % 52) * 2;
    unsigned val = 0u;
    if (vc < VV) {
      float f0 = 0.f, f1 = 0.f;
      if (u0 < UU)
        f0 = expf(att_s[u0 * VV + vc] - mxv[vc]) / smv[vc] * al
             + att0[(h * VV + u0 % VV) * VV + vc];
      if (u0 + 1 < UU)
        f1 = expf(att_s[(u0 + 1) * VV + vc] - mxv[vc]) / smv[vc] * al
             + att0[(h * VV + (u0 + 1) % VV) * VV + vc];
      val = pack2(f0, f1);
    }
    dst[i] = val;
  }
}

// ---------------------------------------------------------------------------
// Kernel D v5b: = R14's k_out_mfma5 with the (256,3) bound REMOVED (the bound
// forced VGPR 84 -> massive scratch spill -> 560 MB HBM). Default bounds let
// the allocator keep the live set (~130 VGPR) in registers; 2 blocks/CU.
// ---------------------------------------------------------------------------
__global__ __launch_bounds__(256) void k_out_mfma5(
    const float* __restrict__ x, const unsigned short* __restrict__ attP,
    const float* __restrict__ Wo, const float* __restrict__ b_o,
    const float* __restrict__ g_o, const float* __restrict__ be_o,
    const float* __restrict__ m_o, const float* __restrict__ v_o,
    const float* __restrict__ Wd, const float* __restrict__ b_d,
    const float* __restrict__ g_d, const float* __restrict__ be_d,
    const float* __restrict__ m_d, const float* __restrict__ v_d,
    float* __restrict__ out)
{
  const int n = blockIdx.x / 30, t0 = (blockIdx.x % 30) * TCO;
  __shared__ alignas(16) char uB[28672];                   // xu2 | xsl2[2]
  __shared__ alignas(16) unsigned short attB[2][32][104];  // 13,312 B dbuf
  unsigned short* xu2 = (unsigned short*)uB;               // [(tr*64+c)*104+u]
  const int tid = threadIdx.x;
  const int lane = tid & 63, wid = tid >> 6;
  const int m16 = lane & 15, kg = lane >> 4;

  #define XSLB(b) (uB + (b) * 14336)            // [112] rows x 128B swz

  #define STAGE_XU(tb)                                                         \
    for (int i = tid; i < 2 * 64 * 48; i += 256) {                             \
      const int u0 = (i % 48) * 2, c = (i / 48) & 63, tr = i / (48 * 64);      \
      float f0 = 0.f, f1 = 0.f;                                                \
      if (u0 < UU) {                                                           \
        const int w = u0 / VV, up = u0 % VV, ts = t0 + (tb) + tr + w - 1;      \
        if (ts >= 0 && ts < TT) f0 = x[((n * 64 + c) * TT + ts) * VV + up];    \
      }                                                                        \
      if (u0 + 1 < UU) {                                                       \
        const int u = u0 + 1, w = u / VV, up = u % VV;                         \
        const int ts = t0 + (tb) + tr + w - 1;                                 \
        if (ts >= 0 && ts < TT) f1 = x[((n * 64 + c) * TT + ts) * VV + up];    \
      }                                                                        \
      *(unsigned*)(xu2 + (tr * 64 + c) * 104 + u0) = pack2(f0, f1);            \
    }

  #define STAGE_ATT(hh, buf)                                                   \
    {                                                                          \
      const u32x4* srcv =                                                      \
          (const u32x4*)(attP + ((size_t)(n * HH + (hh)) * 32) * 104);         \
      u32x4* dstv = (u32x4*)&attB[buf][0][0];                                  \
      for (int i = tid; i < 416; i += 256) dstv[i] = srcv[i];                  \
    }

  // ---- prologue: A-frags from xu2 in two 2-t chunks ----
  STAGE_XU(0);
  __syncthreads();
  u32x4 af[4][3];
  if (wid < 2) {
    #pragma unroll
    for (int mt = 0; mt < 4; ++mt)
      #pragma unroll
      for (int ks = 0; ks < 3; ++ks)
        af[mt][ks] = *(const u32x4*)(xu2 + (wid * 64 + mt * 16 + m16) * 104 +
                                     ks * 32 + kg * 8);
  }
  __syncthreads();   // chunk-1 reads drained before overwrite
  STAGE_XU(2);
  STAGE_ATT(0, 0);
  __syncthreads();
  if (wid >= 2) {
    #pragma unroll
    for (int mt = 0; mt < 4; ++mt)
      #pragma unroll
      for (int ks = 0; ks < 3; ++ks)
        af[mt][ks] = *(const u32x4*)(xu2 + ((wid - 2) * 64 + mt * 16 + m16) * 104 +
                                     ks * 32 + kg * 8);
  }
  __syncthreads();   // FENCE: all xu2 reads drained; uB becomes xsl2
  // zero junk rows (tv 100..111) of BOTH xsl buffers (never rewritten)
  for (int i = tid; i < 2 * 12 * 64; i += 256) {
    const int b = i / (12 * 64), r = i % (12 * 64);
    *(unsigned short*)(XSLB(b) + (100 + (r >> 6)) * 128 + ((r & 63) * 2)) = 0;
  }

  // per-thread BN scales for this thread's two A-frag rows (d = wid*32+mt*16+m16)
  float so_m[2], sd_m[2];
  #pragma unroll
  for (int mt = 0; mt < 2; ++mt) {
    const int d = wid * 32 + mt * 16 + m16;
    so_m[mt] = g_o[d] * rsqrtf(v_o[d] + 1e-5f);
    sd_m[mt] = g_d[d] * rsqrtf(v_d[d] + 1e-5f);
  }

  f32x4 acc2[2][7];
  #pragma unroll
  for (int mt = 0; mt < 2; ++mt)
    #pragma unroll
    for (int nt = 0; nt < 7; ++nt) acc2[mt][nt] = (f32x4)0.f;

  for (int h = 0; h <= HH; ++h) {
    const int pb = h & 1;
    char* xs = XSLB(pb);
    // stage2 A-frags direct from global (issued early; latency hides under
    // stage1 MFMAs). Layout identical to the old wol path.
    u32x4 a2[2][2];
    #pragma unroll
    for (int mt = 0; mt < 2; ++mt) {
      const int d = wid * 32 + mt * 16 + m16;
      const float sc = (h < HH) ? so_m[mt] : sd_m[mt];
      const float* wr = (h < HH) ? (Wo + (size_t)d * 512 + h * 64)
                                 : (Wd + (size_t)d * 64);
      #pragma unroll
      for (int ks = 0; ks < 2; ++ks) {
        const float4 p0 = *(const float4*)(wr + ks * 32 + kg * 8);
        const float4 p1 = *(const float4*)(wr + ks * 32 + kg * 8 + 4);
        u32x4 f;
        f[0] = pack2(p0.x * sc, p0.y * sc); f[1] = pack2(p0.z * sc, p0.w * sc);
        f[2] = pack2(p1.x * sc, p1.y * sc); f[3] = pack2(p1.z * sc, p1.w * sc);
        a2[mt][ks] = f;
      }
    }
    if (h + 1 < HH) { STAGE_ATT(h + 1, (h + 1) & 1); }
    f32x4 a1[4][2];
    if (h < HH) {
      u32x4 bfr[2][3];
      #pragma unroll
      for (int nt = 0; nt < 2; ++nt)
        #pragma unroll
        for (int ks = 0; ks < 3; ++ks)
          bfr[nt][ks] =
              *(const u32x4*)&attB[pb][nt * 16 + m16][ks * 32 + kg * 8];
      #pragma unroll
      for (int mt = 0; mt < 4; ++mt)
        #pragma unroll
        for (int nt = 0; nt < 2; ++nt) {
          a1[mt][nt] = (f32x4)0.f;
          #pragma unroll
          for (int ks = 0; ks < 3; ++ks)
            a1[mt][nt] = mfma_bf16(af[mt][ks], bfr[nt][ks], a1[mt][nt]);
        }
    }
    // write this h's xs buffer (parity pb; h-1 used 1-pb -> no hazard)
    if (h < HH) {
      #pragma unroll
      for (int mt = 0; mt < 4; ++mt)
        #pragma unroll
        for (int nt = 0; nt < 2; ++nt) {
          const int v = nt * 16 + m16;
          if (v < VV) {
            const int tv = wid * VV + v;
            const int c0 = mt * 16 + kg * 4;
            u32x2 pk;
            pk[0] = pack2(a1[mt][nt][0], a1[mt][nt][1]);
            pk[1] = pack2(a1[mt][nt][2], a1[mt][nt][3]);
            char* p = xs + tv * 128 + ((c0 * 2) ^ ((tv & 7) << 4));
            *(u32x2*)p = pk;
          }
        }
    } else {
      for (int i = tid; i < 6400; i += 256) {
        const int c = i / 100, j = i % 100;
        const float f = x[((size_t)(n * 64 + c) * TT + t0) * VV + j];
        *(unsigned short*)(xs + j * 128 + ((c * 2) ^ ((j & 7) << 4))) =
            f2bu(f);
      }
    }
    __syncthreads();   // single barrier: xs writes(pb) -> reads(pb)
    #pragma unroll
    for (int nt = 0; nt < 7; ++nt) {
      const int tv = nt * 16 + m16;
      const u32x4 b0 = *(const u32x4*)(xs + tv * 128 +
                        (((kg * 8) * 2) ^ ((tv & 7) << 4)));
      const u32x4 b1 = *(const u32x4*)(xs + tv * 128 +
                        (((32 + kg * 8) * 2) ^ ((tv & 7) << 4)));
      #pragma unroll
      for (int mt = 0; mt < 2; ++mt) {
        acc2[mt][nt] = mfma_bf16(a2[mt][0], b0, acc2[mt][nt]);
        acc2[mt][nt] = mfma_bf16(a2[mt][1], b1, acc2[mt][nt]);
      }
    }
  }

  #pragma unroll
  for (int mt = 0; mt < 2; ++mt) {
    float cc[4];
    #pragma unroll
    for (int i = 0; i < 4; ++i) {
      const int d = wid * 32 + mt * 16 + kg * 4 + i;
      const float so2 = g_o[d] * rsqrtf(v_o[d] + 1e-5f);
      const float sd2 = g_d[d] * rsqrtf(v_d[d] + 1e-5f);
      cc[i] = b_o[d] * so2 + be_o[d] - m_o[d] * so2
            + b_d[d] * sd2 + be_d[d] - m_d[d] * sd2;
    }
    #pragma unroll
    for (int nt = 0; nt < 7; ++nt) {
      const int tv = nt * 16 + m16;
      if (tv < 100) {
        const int t = t0 + tv / VV, v = tv % VV;
        #pragma unroll
        for (int i = 0; i < 4; ++i) {
          const int d = wid * 32 + mt * 16 + kg * 4 + i;
          const float z = acc2[mt][nt][i] + cc[i];
          out[((n * DIMD + d) * TT + t) * VV + v] = (z >= 0.f) ? z : 0.1f * z;
        }
      }
    }
  }
  #undef STAGE_XU
  #undef STAGE_ATT
  #undef XSLB
}

// ---------------------------------------------------------------------------
extern "C" void kernel_launch(void* const* d_in, const int* in_sizes, int n_in,
                              void* d_out, int out_size, void* d_ws, size_t ws_size,
                              hipStream_t stream)
{
  (void)in_sizes; (void)n_in; (void)out_size; (void)ws_size;
  const float* x     = (const float*)d_in[0];
  const float* Wq    = (const float*)d_in[1];
  const float* bq    = (const float*)d_in[2];
  const float* Wk    = (const float*)d_in[3];
  const float* bk    = (const float*)d_in[4];
  const float* We    = (const float*)d_in[5];
  const float* be    = (const float*)d_in[6];
  const float* G     = (const float*)d_in[7];
  const float* sepe  = (const float*)d_in[8];
  const float* att0  = (const float*)d_in[9];
  const float* alpha = (const float*)d_in[10];
  const float* beta  = (const float*)d_in[11];
  const float* Wo    = (const float*)d_in[12];
  const float* b_o   = (const float*)d_in[13];
  const float* g_o   = (const float*)d_in[14];
  const float* be_o  = (const float*)d_in[15];
  const float* m_o   = (const float*)d_in[16];
  const float* v_o   = (const float*)d_in[17];
  const float* Wd    = (const float*)d_in[18];
  const float* b_d   = (const float*)d_in[19];
  const float* g_d   = (const float*)d_in[20];
  const float* be_d  = (const float*)d_in[21];
  const float* m_d   = (const float*)d_in[22];
  const float* v_d   = (const float*)d_in[23];
  const int*   dism  = (const int*)d_in[24];
  const float* disg  = (const float*)d_in[25];

  // Workspace: qy @0 (49.152 MB), kk @49,152,000, attP @98,304,000 (3.41 MB)
  char* ws = (char*)d_ws;
  bf16* qy   = (bf16*)(ws);
  bf16* kkp  = (bf16*)(ws + 49152000);
  unsigned short* attP = (unsigned short*)(ws + 98304000);

  k_qke_mfma6<<<NB * 30, 256, 0, stream>>>(x, Wq, bq, Wk, bk, We, be, G, beta,
                                           sepe, dism, qy, kkp);
  k_att<<<NB * HH, 256, 0, stream>>>(qy, kkp, bq, disg, att0, alpha, attP);
  k_out_mfma5<<<NB * 30, 256, 0, stream>>>(x, attP, Wo, b_o, g_o, be_o, m_o, v_o,
                                           Wd, b_d, g_d, be_d, m_d, v_d, (float*)d_out);
}

// Round 16
// 459.481 us; speedup vs baseline: 1.6845x; 1.4260x over previous
//
#include <hip/hip_runtime.h>
#include <hip/hip_bf16.h>
#include <math.h>

// Problem constants (fixed by the reference)
#define NB   64     // batch
#define CIN  64     // input channels
#define DIMD 128    // q/k/e channels
#define TT   120    // time
#define VV   25     // joints
#define HH   8      // heads
#define DHD  16     // DIM/H
#define WW   3      // temporal window
#define UU   75     // W*V
#define TC2  12     // t-chunk in MFMA attention kernel (120 = 10*12)
#define TCO  4      // t-chunk in output kernel (120 = 4*30)

typedef __hip_bfloat16 bf16;
typedef float        f32x4  __attribute__((ext_vector_type(4)));
typedef unsigned int u32x4  __attribute__((ext_vector_type(4)));
typedef unsigned int u32x2  __attribute__((ext_vector_type(2)));
typedef __bf16       bf16x8 __attribute__((ext_vector_type(8)));

__device__ __forceinline__ float b2f(bf16 v)  { return __bfloat162float(v); }
__device__ __forceinline__ bf16  f2b(float v) { return __float2bfloat16(v); }

__device__ __forceinline__ unsigned short f2bu(float f) {
  unsigned u = __builtin_bit_cast(unsigned, f);
  return (unsigned short)((u + 0x7fffu + ((u >> 16) & 1u)) >> 16);  // RNE
}
__device__ __forceinline__ float bfu(unsigned short s) {
  unsigned u = ((unsigned)s) << 16;
  return __builtin_bit_cast(float, u);
}
__device__ __forceinline__ unsigned pack2(float a, float b) {
  return ((unsigned)f2bu(b) << 16) | (unsigned)f2bu(a);
}

// BUILTIN MFMA (R11 lesson: asm-wrapped MFMA is invisible to the GCN hazard
// recognizer -> missing MFMA->VALU wait-states -> silent corruption).
__device__ __forceinline__ f32x4 mfma_bf16(u32x4 a, u32x4 b, f32x4 d) {
  return __builtin_amdgcn_mfma_f32_16x16x32_bf16(
      __builtin_bit_cast(bf16x8, a), __builtin_bit_cast(bf16x8, b), d, 0, 0, 0);
}

// ---------------------------------------------------------------------------
// Fused A+B v6 (R15-verbatim, passing)
// ---------------------------------------------------------------------------
__global__ __launch_bounds__(256, 3) void k_qke_mfma6(
    const float* __restrict__ x,
    const float* __restrict__ Wq, const float* __restrict__ bq,
    const float* __restrict__ Wk, const float* __restrict__ bk,
    const float* __restrict__ We, const float* __restrict__ be,
    const float* __restrict__ G,  const float* __restrict__ beta,
    const float* __restrict__ se_pe, const int* __restrict__ dis,
    bf16* __restrict__ qy, bf16* __restrict__ kkp)
{
  const int n = blockIdx.x / 30, t0 = (blockIdx.x % 30) * 4;
  __shared__ alignas(16) char uA[26624];                 // xl | yTG
  __shared__ alignas(16) unsigned short yT[112][64];     // [tv][c] swz
  __shared__ alignas(16) float spl[5][64];
  __shared__ alignas(16) int   dml[25][25];
  __shared__ alignas(16) float Gl[25][26];
  __shared__ alignas(16) float gsum[32];
  __shared__ alignas(16) float biasb[384];               // bq|bk|be

  float* xl  = (float*)uA;                               // [4][64][26] f32
  char*  yTG = uA;                                       // [112] x 128B swz
  #define XL(t, c, v) xl[(((t) * 64 + (c)) * 26) + (v)]

  const int tid = threadIdx.x;
  {
    const float* xb = x + (size_t)n * 192000 + t0 * 25;  // x[n][c][t0+t][v]
    for (int i = tid; i < 6400; i += 256) {
      const int c = i / 100, j = i % 100, t = j / 25, v = j % 25;
      XL(t, c, v) = xb[c * 3000 + j];
    }
  }
  for (int i = tid; i < 320; i += 256) spl[i / 64][i % 64] = se_pe[i];
  for (int i = tid; i < 625; i += 256) dml[i / 25][i % 25] = dis[i];
  for (int i = tid; i < 625; i += 256) Gl[i / 25][i % 25] = G[i];
  if (tid < 25) {
    float s = 0.f;
    for (int u = 0; u < 25; ++u) s += G[u * 25 + tid];
    gsum[tid] = s;
  }
  for (int i = tid; i < 384; i += 256)
    biasb[i] = (i < 128) ? bq[i] : (i < 256 ? bk[i - 128] : be[i - 256]);
  for (int i = tid; i < 12 * 64; i += 256)               // yT junk rows -> 0
    yT[100 + (i >> 6)][i & 63] = 0;
  __syncthreads();

  const int lane = tid & 63, wid = tid >> 6;
  const int m16 = lane & 15, kg = lane >> 4;

  #define LOAD_WFRAGS(af, Wsrc, SC)                                            \
    _Pragma("unroll")                                                          \
    for (int mt = 0; mt < 2; ++mt) {                                           \
      const int d_ = wid * 32 + mt * 16 + m16;                                 \
      _Pragma("unroll")                                                        \
      for (int ks = 0; ks < 2; ++ks) {                                         \
        const float4 p0 = *(const float4*)((Wsrc) + d_ * 64 + ks * 32 + kg * 8);     \
        const float4 p1 = *(const float4*)((Wsrc) + d_ * 64 + ks * 32 + kg * 8 + 4); \
        u32x4 f;                                                               \
        f[0] = pack2(p0.x * (SC), p0.y * (SC));                                \
        f[1] = pack2(p0.z * (SC), p0.w * (SC));                                \
        f[2] = pack2(p1.x * (SC), p1.y * (SC));                                \
        f[3] = pack2(p1.z * (SC), p1.w * (SC));                                \
        af[mt][ks] = f;                                                        \
      }                                                                        \
    }

  // ---- phase 1: yT = x + pe + struct-enc ----
  for (int idx = tid; idx < 6400; idx += 256) {
    const int c = idx & 63, tv = idx >> 6;
    const int t = tv / 25, v = tv % 25;
    const float dv = expf(-(float)(c & ~1) * (logf(10000.0f) / 64.0f));
    float acc = XL(t, c, v) +
                ((c & 1) ? cosf((float)v * dv) : sinf((float)v * dv));
    #pragma unroll
    for (int u = 0; u < 25; ++u)
      acc = fmaf(XL(t, c, u), spl[dml[u][v]][c], acc);
    *(unsigned short*)((char*)yT + tv * 128 + ((c * 2) ^ ((tv & 7) << 4))) =
        f2bu(acc);
  }
  __syncthreads();   // yT ready; xl DEAD (uA becomes yTG)

  // ---- phase 1b: yTG = y @ G ----
  for (int i = tid; i < 12 * 64; i += 256)
    *(unsigned short*)(yTG + (100 + (i >> 6)) * 128 + ((i & 63) * 2)) = 0;
  for (int idx = tid; idx < 6400; idx += 256) {
    const int c = idx & 63, tv = idx >> 6;
    const int t = tv / 25, v = tv % 25;
    float acc = 0.f;
    #pragma unroll
    for (int u = 0; u < 25; ++u) {
      const int ru = t * 25 + u;
      const float yv = bfu(*(const unsigned short*)((const char*)yT + ru * 128 +
                            ((c * 2) ^ ((ru & 7) << 4))));
      acc = fmaf(yv, Gl[u][v], acc);
    }
    *(unsigned short*)(yTG + tv * 128 + ((c * 2) ^ ((tv & 7) << 4))) =
        f2bu(acc);
  }
  __syncthreads();   // yTG ready — LAST barrier; GEMMs are straight-line

  bf16* qyb = qy  + (size_t)n * 384000 + t0 * 25;
  bf16* kkb = kkp + (size_t)n * 384000 + t0 * 25;
  const float betav = beta[0];

  // ---- q-GEMM ----
  {
    u32x4 aq[2][2];
    LOAD_WFRAGS(aq, Wq, 1.0f);
    for (int nt = 0; nt < 7; ++nt) {
      const int tv = nt * 16 + m16;
      const u32x4 b0 = *(const u32x4*)((const char*)yT + tv * 128 +
                        (((kg * 8) * 2) ^ ((tv & 7) << 4)));
      const u32x4 b1 = *(const u32x4*)((const char*)yT + tv * 128 +
                        (((32 + kg * 8) * 2) ^ ((tv & 7) << 4)));
      #pragma unroll
      for (int mt = 0; mt < 2; ++mt) {
        f32x4 acc = (f32x4)0.f;
        acc = mfma_bf16(aq[mt][0], b0, acc);
        acc = mfma_bf16(aq[mt][1], b1, acc);
        if (tv < 100) {
          const int dr = wid * 32 + mt * 16 + kg * 4;
          #pragma unroll
          for (int i2 = 0; i2 < 4; ++i2)
            qyb[(size_t)(dr + i2) * 3000 + tv] = f2b(acc[i2] + biasb[dr + i2]);
        }
      }
    }
  }

  // ---- k-GEMM into persistent kacc ----
  f32x4 kacc[2][7];
  #pragma unroll
  for (int mt = 0; mt < 2; ++mt)
    #pragma unroll
    for (int nt = 0; nt < 7; ++nt) kacc[mt][nt] = (f32x4)0.f;
  {
    u32x4 ak[2][2];
    LOAD_WFRAGS(ak, Wk, 1.0f);
    for (int nt = 0; nt < 7; ++nt) {
      const int tv = nt * 16 + m16;
      const u32x4 b0 = *(const u32x4*)((const char*)yT + tv * 128 +
                        (((kg * 8) * 2) ^ ((tv & 7) << 4)));
      const u32x4 b1 = *(const u32x4*)((const char*)yT + tv * 128 +
                        (((32 + kg * 8) * 2) ^ ((tv & 7) << 4)));
      #pragma unroll
      for (int mt = 0; mt < 2; ++mt) {
        kacc[mt][nt] = mfma_bf16(ak[mt][0], b0, kacc[mt][nt]);
        kacc[mt][nt] = mfma_bf16(ak[mt][1], b1, kacc[mt][nt]);
      }
    }
  }

  // ---- e-GEMM (beta*We) on yTG, accumulate, store kk ----
  {
    u32x4 ae[2][2];
    LOAD_WFRAGS(ae, We, betav);
    for (int nt = 0; nt < 7; ++nt) {
      const int tv = nt * 16 + m16;
      const u32x4 b0 = *(const u32x4*)(yTG + tv * 128 +
                        (((kg * 8) * 2) ^ ((tv & 7) << 4)));
      const u32x4 b1 = *(const u32x4*)(yTG + tv * 128 +
                        (((32 + kg * 8) * 2) ^ ((tv & 7) << 4)));
      #pragma unroll
      for (int mt = 0; mt < 2; ++mt) {
        kacc[mt][nt] = mfma_bf16(ae[mt][0], b0, kacc[mt][nt]);
        kacc[mt][nt] = mfma_bf16(ae[mt][1], b1, kacc[mt][nt]);
        if (tv < 100) {
          const int vv = tv % 25;
          const int dr = wid * 32 + mt * 16 + kg * 4;
          #pragma unroll
          for (int i2 = 0; i2 < 4; ++i2)
            kkb[(size_t)(dr + i2) * 3000 + tv] =
                f2b(kacc[mt][nt][i2] + biasb[128 + dr + i2] +
                    betav * biasb[256 + dr + i2] * gsum[vv]);
        }
      }
    }
  }
  #undef LOAD_WFRAGS
  #undef XL
}

// ---------------------------------------------------------------------------
// Kernel C v2 (MFMA): att[u,v] = sum_{dh,t} q[dh,t,u]*kk[dh,t,v]
// K packed k=tt*16+dh, 10 chunks of 12 t. A=qsA[u][k], B=ksB[v][k] (pitch 200
// u16, ~2-way banks). Frag/D mappings identical to verified k_out stage1.
// Epilogue: mask -> softmax(u) -> alpha*p+att0 -> padded attP (R13 pattern).
// ---------------------------------------------------------------------------
__global__ __launch_bounds__(256) void k_att_mfma(
    const bf16* __restrict__ qy, const bf16* __restrict__ kkp,
    const float* __restrict__ bq, const float* __restrict__ disg,
    const float* __restrict__ att0, const float* __restrict__ alpha,
    unsigned short* __restrict__ attP)
{
  const int n = blockIdx.x / HH, h = blockIdx.x % HH;
  __shared__ alignas(16) unsigned short qsA[80][200];  // [u][k] bf16 bits
  __shared__ alignas(16) unsigned short ksB[32][200];  // [v][k] bf16 bits
  __shared__ alignas(16) float att_s[80][28];
  __shared__ float mxv[32], smv[32];
  const int tid = threadIdx.x;
  const int lane = tid & 63, wid = tid >> 6;
  const int m16 = lane & 15, kg = lane >> 4;

  const unsigned short* qyb =
      (const unsigned short*)(qy + ((size_t)(n * DIMD + h * DHD)) * TT * VV);
  const unsigned short* kkb =
      (const unsigned short*)(kkp + ((size_t)(n * DIMD + h * DHD)) * TT * VV);

  // wave wid owns output tiles tidx = wid + 4*s (s=0..2), tidx<10;
  // tile -> (mtile = tidx>>1 in 0..4, ntile = tidx&1)
  f32x4 acc[3];
  #pragma unroll
  for (int s = 0; s < 3; ++s) acc[s] = (f32x4)0.f;

  for (int c = 0; c < 10; ++c) {
    const int t0 = c * TC2;
    __syncthreads();   // prev chunk's frag reads drained
    // stage: 224 q source-rows (dh, tq=t0-1..t0+12) + 192 k source-rows
    for (int it = tid; it < 416; it += 256) {
      if (it < 224) {
        const int dh = it / 14, j = it % 14, tq = t0 + j - 1;
        unsigned short vals[25];
        if (tq >= 0 && tq < TT) {
          const unsigned short* src = qyb + ((size_t)dh * TT + tq) * VV;
          #pragma unroll
          for (int u = 0; u < 25; ++u) vals[u] = src[u];
        } else {
          const unsigned short bqv = f2bu(bq[h * DHD + dh]);
          #pragma unroll
          for (int u = 0; u < 25; ++u) vals[u] = bqv;
        }
        #pragma unroll
        for (int w = 0; w < 3; ++w) {
          const int tt = tq - t0 - w + 1;     // q[dh,t0+tt,u=w*25+u'] = qy[dh,tq,u']
          if (tt >= 0 && tt < TC2) {
            const int col = tt * 16 + dh;
            #pragma unroll
            for (int u = 0; u < 25; ++u) qsA[w * 25 + u][col] = vals[u];
          }
        }
      } else {
        const int r = it - 224, dh = r / TC2, tt = r % TC2;
        const unsigned short* src = kkb + ((size_t)dh * TT + t0 + tt) * VV;
        const int col = tt * 16 + dh;
        #pragma unroll
        for (int v = 0; v < 25; ++v) ksB[v][col] = src[v];
      }
    }
    __syncthreads();   // tiles ready
    #pragma unroll
    for (int s = 0; s < 3; ++s) {
      const int tidx = wid + 4 * s;
      if (tidx < 10) {
        const int mtile = tidx >> 1, ntile = tidx & 1;
        #pragma unroll
        for (int ks = 0; ks < 6; ++ks) {
          const u32x4 a = *(const u32x4*)&qsA[mtile * 16 + m16][ks * 32 + kg * 8];
          const u32x4 b = *(const u32x4*)&ksB[ntile * 16 + m16][ks * 32 + kg * 8];
          acc[s] = mfma_bf16(a, b, acc[s]);
        }
      }
    }
  }
  __syncthreads();
  // D -> att_s (D row = mtile*16 + kg*4+i, col = ntile*16 + m16)
  #pragma unroll
  for (int s = 0; s < 3; ++s) {
    const int tidx = wid + 4 * s;
    if (tidx < 10) {
      const int mtile = tidx >> 1, ntile = tidx & 1;
      const int v = ntile * 16 + m16;
      if (v < VV) {
        #pragma unroll
        for (int i = 0; i < 4; ++i)
          att_s[mtile * 16 + kg * 4 + i][v] = acc[s][i];
      }
    }
  }
  __syncthreads();
  // mask + 1/1920 scale
  const float inv = 1.0f / (float)(DHD * TT);
  for (int i = tid; i < UU * VV; i += 256) {
    const int u = i / VV, v = i % VV;
    const bool m = disg[(h * VV + u % VV) * VV + v] > 0.f;
    att_s[u][v] = m ? att_s[u][v] * inv : -9e15f;
  }
  __syncthreads();
  if (tid < VV) {
    float mx = -INFINITY;
    for (int u = 0; u < UU; ++u) mx = fmaxf(mx, att_s[u][tid]);
    float sm = 0.f;
    for (int u = 0; u < UU; ++u) sm += expf(att_s[u][tid] - mx);
    mxv[tid] = mx; smv[tid] = sm;
  }
  __syncthreads();
  const float al = alpha[0];
  unsigned* dst = (unsigned*)(attP + ((size_t)(n * HH + h) * 32) * 104);
  for (int i = tid; i < 1664; i += 256) {     // 32 x 52 u32 (= 104 u16)
    const int vc = i / 52, u0 = (i % 52) * 2;
    unsigned val = 0u;
    if (vc < VV) {
      float f0 = 0.f, f1 = 0.f;
      if (u0 < UU)
        f0 = expf(att_s[u0][vc] - mxv[vc]) / smv[vc] * al
             + att0[(h * VV + u0 % VV) * VV + vc];
      if (u0 + 1 < UU)
        f1 = expf(att_s[u0 + 1][vc] - mxv[vc]) / smv[vc] * al
             + att0[(h * VV + (u0 + 1) % VV) * VV + vc];
      val = pack2(f0, f1);
    }
    dst[i] = val;
  }
}

// ---------------------------------------------------------------------------
// Kernel D v5b (R15-verbatim, passing)
// ---------------------------------------------------------------------------
__global__ __launch_bounds__(256) void k_out_mfma5(
    const float* __restrict__ x, const unsigned short* __restrict__ attP,
    const float* __restrict__ Wo, const float* __restrict__ b_o,
    const float* __restrict__ g_o, const float* __restrict__ be_o,
    const float* __restrict__ m_o, const float* __restrict__ v_o,
    const float* __restrict__ Wd, const float* __restrict__ b_d,
    const float* __restrict__ g_d, const float* __restrict__ be_d,
    const float* __restrict__ m_d, const float* __restrict__ v_d,
    float* __restrict__ out)
{
  const int n = blockIdx.x / 30, t0 = (blockIdx.x % 30) * TCO;
  __shared__ alignas(16) char uB[28672];                   // xu2 | xsl2[2]
  __shared__ alignas(16) unsigned short attB[2][32][104];  // 13,312 B dbuf
  unsigned short* xu2 = (unsigned short*)uB;               // [(tr*64+c)*104+u]
  const int tid = threadIdx.x;
  const int lane = tid & 63, wid = tid >> 6;
  const int m16 = lane & 15, kg = lane >> 4;

  #define XSLB(b) (uB + (b) * 14336)            // [112] rows x 128B swz

  #define STAGE_XU(tb)                                                         \
    for (int i = tid; i < 2 * 64 * 48; i += 256) {                             \
      const int u0 = (i % 48) * 2, c = (i / 48) & 63, tr = i / (48 * 64);      \
      float f0 = 0.f, f1 = 0.f;                                                \
      if (u0 < UU) {                                                           \
        const int w = u0 / VV, up = u0 % VV, ts = t0 + (tb) + tr + w - 1;      \
        if (ts >= 0 && ts < TT) f0 = x[((n * 64 + c) * TT + ts) * VV + up];    \
      }                                                                        \
      if (u0 + 1 < UU) {                                                       \
        const int u = u0 + 1, w = u / VV, up = u % VV;                         \
        const int ts = t0 + (tb) + tr + w - 1;                                 \
        if (ts >= 0 && ts < TT) f1 = x[((n * 64 + c) * TT + ts) * VV + up];    \
      }                                                                        \
      *(unsigned*)(xu2 + (tr * 64 + c) * 104 + u0) = pack2(f0, f1);            \
    }

  #define STAGE_ATT(hh, buf)                                                   \
    {                                                                          \
      const u32x4* srcv =                                                      \
          (const u32x4*)(attP + ((size_t)(n * HH + (hh)) * 32) * 104);         \
      u32x4* dstv = (u32x4*)&attB[buf][0][0];                                  \
      for (int i = tid; i < 416; i += 256) dstv[i] = srcv[i];                  \
    }

  // ---- prologue: A-frags from xu2 in two 2-t chunks ----
  STAGE_XU(0);
  __syncthreads();
  u32x4 af[4][3];
  if (wid < 2) {
    #pragma unroll
    for (int mt = 0; mt < 4; ++mt)
      #pragma unroll
      for (int ks = 0; ks < 3; ++ks)
        af[mt][ks] = *(const u32x4*)(xu2 + (wid * 64 + mt * 16 + m16) * 104 +
                                     ks * 32 + kg * 8);
  }
  __syncthreads();   // chunk-1 reads drained before overwrite
  STAGE_XU(2);
  STAGE_ATT(0, 0);
  __syncthreads();
  if (wid >= 2) {
    #pragma unroll
    for (int mt = 0; mt < 4; ++mt)
      #pragma unroll
      for (int ks = 0; ks < 3; ++ks)
        af[mt][ks] = *(const u32x4*)(xu2 + ((wid - 2) * 64 + mt * 16 + m16) * 104 +
                                     ks * 32 + kg * 8);
  }
  __syncthreads();   // FENCE: all xu2 reads drained; uB becomes xsl2
  // zero junk rows (tv 100..111) of BOTH xsl buffers (never rewritten)
  for (int i = tid; i < 2 * 12 * 64; i += 256) {
    const int b = i / (12 * 64), r = i % (12 * 64);
    *(unsigned short*)(XSLB(b) + (100 + (r >> 6)) * 128 + ((r & 63) * 2)) = 0;
  }

  // per-thread BN scales for this thread's two A-frag rows (d = wid*32+mt*16+m16)
  float so_m[2], sd_m[2];
  #pragma unroll
  for (int mt = 0; mt < 2; ++mt) {
    const int d = wid * 32 + mt * 16 + m16;
    so_m[mt] = g_o[d] * rsqrtf(v_o[d] + 1e-5f);
    sd_m[mt] = g_d[d] * rsqrtf(v_d[d] + 1e-5f);
  }

  f32x4 acc2[2][7];
  #pragma unroll
  for (int mt = 0; mt < 2; ++mt)
    #pragma unroll
    for (int nt = 0; nt < 7; ++nt) acc2[mt][nt] = (f32x4)0.f;

  for (int h = 0; h <= HH; ++h) {
    const int pb = h & 1;
    char* xs = XSLB(pb);
    u32x4 a2[2][2];
    #pragma unroll
    for (int mt = 0; mt < 2; ++mt) {
      const int d = wid * 32 + mt * 16 + m16;
      const float sc = (h < HH) ? so_m[mt] : sd_m[mt];
      const float* wr = (h < HH) ? (Wo + (size_t)d * 512 + h * 64)
                                 : (Wd + (size_t)d * 64);
      #pragma unroll
      for (int ks = 0; ks < 2; ++ks) {
        const float4 p0 = *(const float4*)(wr + ks * 32 + kg * 8);
        const float4 p1 = *(const float4*)(wr + ks * 32 + kg * 8 + 4);
        u32x4 f;
        f[0] = pack2(p0.x * sc, p0.y * sc); f[1] = pack2(p0.z * sc, p0.w * sc);
        f[2] = pack2(p1.x * sc, p1.y * sc); f[3] = pack2(p1.z * sc, p1.w * sc);
        a2[mt][ks] = f;
      }
    }
    if (h + 1 < HH) { STAGE_ATT(h + 1, (h + 1) & 1); }
    f32x4 a1[4][2];
    if (h < HH) {
      u32x4 bfr[2][3];
      #pragma unroll
      for (int nt = 0; nt < 2; ++nt)
        #pragma unroll
        for (int ks = 0; ks < 3; ++ks)
          bfr[nt][ks] =
              *(const u32x4*)&attB[pb][nt * 16 + m16][ks * 32 + kg * 8];
      #pragma unroll
      for (int mt = 0; mt < 4; ++mt)
        #pragma unroll
        for (int nt = 0; nt < 2; ++nt) {
          a1[mt][nt] = (f32x4)0.f;
          #pragma unroll
          for (int ks = 0; ks < 3; ++ks)
            a1[mt][nt] = mfma_bf16(af[mt][ks], bfr[nt][ks], a1[mt][nt]);
        }
    }
    if (h < HH) {
      #pragma unroll
      for (int mt = 0; mt < 4; ++mt)
        #pragma unroll
        for (int nt = 0; nt < 2; ++nt) {
          const int v = nt * 16 + m16;
          if (v < VV) {
            const int tv = wid * VV + v;
            const int c0 = mt * 16 + kg * 4;
            u32x2 pk;
            pk[0] = pack2(a1[mt][nt][0], a1[mt][nt][1]);
            pk[1] = pack2(a1[mt][nt][2], a1[mt][nt][3]);
            char* p = xs + tv * 128 + ((c0 * 2) ^ ((tv & 7) << 4));
            *(u32x2*)p = pk;
          }
        }
    } else {
      for (int i = tid; i < 6400; i += 256) {
        const int c = i / 100, j = i % 100;
        const float f = x[((size_t)(n * 64 + c) * TT + t0) * VV + j];
        *(unsigned short*)(xs + j * 128 + ((c * 2) ^ ((j & 7) << 4))) =
            f2bu(f);
      }
    }
    __syncthreads();   // single barrier: xs writes(pb) -> reads(pb)
    #pragma unroll
    for (int nt = 0; nt < 7; ++nt) {
      const int tv = nt * 16 + m16;
      const u32x4 b0 = *(const u32x4*)(xs + tv * 128 +
                        (((kg * 8) * 2) ^ ((tv & 7) << 4)));
      const u32x4 b1 = *(const u32x4*)(xs + tv * 128 +
                        (((32 + kg * 8) * 2) ^ ((tv & 7) << 4)));
      #pragma unroll
      for (int mt = 0; mt < 2; ++mt) {
        acc2[mt][nt] = mfma_bf16(a2[mt][0], b0, acc2[mt][nt]);
        acc2[mt][nt] = mfma_bf16(a2[mt][1], b1, acc2[mt][nt]);
      }
    }
  }

  #pragma unroll
  for (int mt = 0; mt < 2; ++mt) {
    float cc[4];
    #pragma unroll
    for (int i = 0; i < 4; ++i) {
      const int d = wid * 32 + mt * 16 + kg * 4 + i;
      const float so2 = g_o[d] * rsqrtf(v_o[d] + 1e-5f);
      const float sd2 = g_d[d] * rsqrtf(v_d[d] + 1e-5f);
      cc[i] = b_o[d] * so2 + be_o[d] - m_o[d] * so2
            + b_d[d] * sd2 + be_d[d] - m_d[d] * sd2;
    }
    #pragma unroll
    for (int nt = 0; nt < 7; ++nt) {
      const int tv = nt * 16 + m16;
      if (tv < 100) {
        const int t = t0 + tv / VV, v = tv % VV;
        #pragma unroll
        for (int i = 0; i < 4; ++i) {
          const int d = wid * 32 + mt * 16 + kg * 4 + i;
          const float z = acc2[mt][nt][i] + cc[i];
          out[((n * DIMD + d) * TT + t) * VV + v] = (z >= 0.f) ? z : 0.1f * z;
        }
      }
    }
  }
  #undef STAGE_XU
  #undef STAGE_ATT
  #undef XSLB
}

// ---------------------------------------------------------------------------
extern "C" void kernel_launch(void* const* d_in, const int* in_sizes, int n_in,
                              void* d_out, int out_size, void* d_ws, size_t ws_size,
                              hipStream_t stream)
{
  (void)in_sizes; (void)n_in; (void)out_size; (void)ws_size;
  const float* x     = (const float*)d_in[0];
  const float* Wq    = (const float*)d_in[1];
  const float* bq    = (const float*)d_in[2];
  const float* Wk    = (const float*)d_in[3];
  const float* bk    = (const float*)d_in[4];
  const float* We    = (const float*)d_in[5];
  const float* be    = (const float*)d_in[6];
  const float* G     = (const float*)d_in[7];
  const float* sepe  = (const float*)d_in[8];
  const float* att0  = (const float*)d_in[9];
  const float* alpha = (const float*)d_in[10];
  const float* beta  = (const float*)d_in[11];
  const float* Wo    = (const float*)d_in[12];
  const float* b_o   = (const float*)d_in[13];
  const float* g_o   = (const float*)d_in[14];
  const float* be_o  = (const float*)d_in[15];
  const float* m_o   = (const float*)d_in[16];
  const float* v_o   = (const float*)d_in[17];
  const float* Wd    = (const float*)d_in[18];
  const float* b_d   = (const float*)d_in[19];
  const float* g_d   = (const float*)d_in[20];
  const float* be_d  = (const float*)d_in[21];
  const float* m_d   = (const float*)d_in[22];
  const float* v_d   = (const float*)d_in[23];
  const int*   dism  = (const int*)d_in[24];
  const float* disg  = (const float*)d_in[25];

  // Workspace: qy @0 (49.152 MB), kk @49,152,000, attP @98,304,000 (3.41 MB)
  char* ws = (char*)d_ws;
  bf16* qy   = (bf16*)(ws);
  bf16* kkp  = (bf16*)(ws + 49152000);
  unsigned short* attP = (unsigned short*)(ws + 98304000);

  k_qke_mfma6<<<NB * 30, 256, 0, stream>>>(x, Wq, bq, Wk, bk, We, be, G, beta,
                                           sepe, dism, qy, kkp);
  k_att_mfma<<<NB * HH, 256, 0, stream>>>(qy, kkp, bq, disg, att0, alpha, attP);
  k_out_mfma5<<<NB * 30, 256, 0, stream>>>(x, attP, Wo, b_o, g_o, be_o, m_o, v_o,
                                           Wd, b_d, g_d, be_d, m_d, v_d, (float*)d_out);
}

// Round 17
// 406.820 us; speedup vs baseline: 1.9025x; 1.1294x over previous
//
#include <hip/hip_runtime.h>
#include <hip/hip_bf16.h>
#include <math.h>

// Problem constants (fixed by the reference)
#define NB   64     // batch
#define CIN  64     // input channels
#define DIMD 128    // q/k/e channels
#define TT   120    // time
#define VV   25     // joints
#define HH   8      // heads
#define DHD  16     // DIM/H
#define WW   3      // temporal window
#define UU   75     // W*V
#define TC2  12     // t-chunk in MFMA attention kernel (120 = 10*12)
#define TCO  4      // t-chunk in output kernel (120 = 4*30)

typedef __hip_bfloat16 bf16;
typedef float        f32x4  __attribute__((ext_vector_type(4)));
typedef unsigned int u32x4  __attribute__((ext_vector_type(4)));
typedef unsigned int u32x2  __attribute__((ext_vector_type(2)));
typedef __bf16       bf16x8 __attribute__((ext_vector_type(8)));

__device__ __forceinline__ float b2f(bf16 v)  { return __bfloat162float(v); }
__device__ __forceinline__ bf16  f2b(float v) { return __float2bfloat16(v); }

__device__ __forceinline__ unsigned short f2bu(float f) {
  unsigned u = __builtin_bit_cast(unsigned, f);
  return (unsigned short)((u + 0x7fffu + ((u >> 16) & 1u)) >> 16);  // RNE
}
__device__ __forceinline__ float bfu(unsigned short s) {
  unsigned u = ((unsigned)s) << 16;
  return __builtin_bit_cast(float, u);
}
__device__ __forceinline__ unsigned pack2(float a, float b) {
  return ((unsigned)f2bu(b) << 16) | (unsigned)f2bu(a);
}

// BUILTIN MFMA (R11 lesson: asm-wrapped MFMA is invisible to the GCN hazard
// recognizer -> missing MFMA->VALU wait-states -> silent corruption).
__device__ __forceinline__ f32x4 mfma_bf16(u32x4 a, u32x4 b, f32x4 d) {
  return __builtin_amdgcn_mfma_f32_16x16x32_bf16(
      __builtin_bit_cast(bf16x8, a), __builtin_bit_cast(bf16x8, b), d, 0, 0, 0);
}

// ---------------------------------------------------------------------------
// Pre-pack kernel: weights -> fragment-ordered bf16 tensors (scales folded).
//   woF[h][ks][kg][d][8] = so[d]*Wo[d][h*64+c]   (65536 u16)
//   wdF[ks][kg][d][8]    = sd[d]*Wd[d][c]        ( 8192 u16)
//   wqF/wkF[ks][kg][d][8]= Wq/Wk[d][c]           ( 8192 each)
//   weF[ks][kg][d][8]    = beta*We[d][c]         ( 8192)
// c = ks*32 + kg*8 + j. Frag load = 1 u32x4, 256B-contig per 16-lane group.
// ---------------------------------------------------------------------------
__global__ __launch_bounds__(256) void k_pack_w(
    const float* __restrict__ Wo, const float* __restrict__ g_o,
    const float* __restrict__ v_o,
    const float* __restrict__ Wd, const float* __restrict__ g_d,
    const float* __restrict__ v_d,
    const float* __restrict__ Wq, const float* __restrict__ Wk,
    const float* __restrict__ We, const float* __restrict__ beta,
    unsigned short* __restrict__ woF, unsigned short* __restrict__ wdF,
    unsigned short* __restrict__ wqF, unsigned short* __restrict__ wkF,
    unsigned short* __restrict__ weF)
{
  const int i = blockIdx.x * 256 + threadIdx.x;   // grid covers 98304
  if (i < 65536) {                                 // woF
    const int j = i & 7, d = (i >> 3) & 127, kg = (i >> 10) & 3;
    const int ks = (i >> 12) & 1, h = (i >> 13) & 7;
    const float sc = g_o[d] * rsqrtf(v_o[d] + 1e-5f);
    woF[i] = f2bu(sc * Wo[d * 512 + h * 64 + ks * 32 + kg * 8 + j]);
  } else {
    const int r = i - 65536;                       // 0..32767
    const int which = r >> 13;                     // 0=wd 1=wq 2=wk 3=we
    const int l = r & 8191;
    const int j = l & 7, d = (l >> 3) & 127, kg = (l >> 10) & 3;
    const int ks = (l >> 12) & 1;
    const int c = ks * 32 + kg * 8 + j;
    if (which == 0) {
      const float sc = g_d[d] * rsqrtf(v_d[d] + 1e-5f);
      wdF[l] = f2bu(sc * Wd[d * 64 + c]);
    } else if (which == 1) {
      wqF[l] = f2bu(Wq[d * 64 + c]);
    } else if (which == 2) {
      wkF[l] = f2bu(Wk[d * 64 + c]);
    } else {
      weF[l] = f2bu(beta[0] * We[d * 64 + c]);
    }
  }
}

// ---------------------------------------------------------------------------
// Fused A+B v7: frag loads from pre-packed tensors (coalesced, no pack VALU).
// ---------------------------------------------------------------------------
__global__ __launch_bounds__(256, 3) void k_qke_mfma7(
    const float* __restrict__ x,
    const unsigned short* __restrict__ wqF, const float* __restrict__ bq,
    const unsigned short* __restrict__ wkF, const float* __restrict__ bk,
    const unsigned short* __restrict__ weF, const float* __restrict__ be,
    const float* __restrict__ G,  const float* __restrict__ beta,
    const float* __restrict__ se_pe, const int* __restrict__ dis,
    bf16* __restrict__ qy, bf16* __restrict__ kkp)
{
  const int n = blockIdx.x / 30, t0 = (blockIdx.x % 30) * 4;
  __shared__ alignas(16) char uA[26624];                 // xl | yTG
  __shared__ alignas(16) unsigned short yT[112][64];     // [tv][c] swz
  __shared__ alignas(16) float spl[5][64];
  __shared__ alignas(16) int   dml[25][25];
  __shared__ alignas(16) float Gl[25][26];
  __shared__ alignas(16) float gsum[32];
  __shared__ alignas(16) float biasb[384];               // bq|bk|be

  float* xl  = (float*)uA;                               // [4][64][26] f32
  char*  yTG = uA;                                       // [112] x 128B swz
  #define XL(t, c, v) xl[(((t) * 64 + (c)) * 26) + (v)]

  const int tid = threadIdx.x;
  {
    const float* xb = x + (size_t)n * 192000 + t0 * 25;  // x[n][c][t0+t][v]
    for (int i = tid; i < 6400; i += 256) {
      const int c = i / 100, j = i % 100, t = j / 25, v = j % 25;
      XL(t, c, v) = xb[c * 3000 + j];
    }
  }
  for (int i = tid; i < 320; i += 256) spl[i / 64][i % 64] = se_pe[i];
  for (int i = tid; i < 625; i += 256) dml[i / 25][i % 25] = dis[i];
  for (int i = tid; i < 625; i += 256) Gl[i / 25][i % 25] = G[i];
  if (tid < 25) {
    float s = 0.f;
    for (int u = 0; u < 25; ++u) s += G[u * 25 + tid];
    gsum[tid] = s;
  }
  for (int i = tid; i < 384; i += 256)
    biasb[i] = (i < 128) ? bq[i] : (i < 256 ? bk[i - 128] : be[i - 256]);
  for (int i = tid; i < 12 * 64; i += 256)               // yT junk rows -> 0
    yT[100 + (i >> 6)][i & 63] = 0;
  __syncthreads();

  const int lane = tid & 63, wid = tid >> 6;
  const int m16 = lane & 15, kg = lane >> 4;

  // coalesced frag load from pre-packed [ks][kg][d][8] tensor
  #define LOAD_PFRAGS(af, Fsrc)                                                \
    _Pragma("unroll")                                                          \
    for (int mt = 0; mt < 2; ++mt) {                                           \
      const int d_ = wid * 32 + mt * 16 + m16;                                 \
      _Pragma("unroll")                                                        \
      for (int ks = 0; ks < 2; ++ks)                                           \
        af[mt][ks] = *(const u32x4*)((Fsrc) +                                  \
                      (((ks * 4 + kg) * 128 + d_) << 3));                      \
    }

  // ---- phase 1: yT = x + pe + struct-enc ----
  for (int idx = tid; idx < 6400; idx += 256) {
    const int c = idx & 63, tv = idx >> 6;
    const int t = tv / 25, v = tv % 25;
    const float dv = expf(-(float)(c & ~1) * (logf(10000.0f) / 64.0f));
    float acc = XL(t, c, v) +
                ((c & 1) ? cosf((float)v * dv) : sinf((float)v * dv));
    #pragma unroll
    for (int u = 0; u < 25; ++u)
      acc = fmaf(XL(t, c, u), spl[dml[u][v]][c], acc);
    *(unsigned short*)((char*)yT + tv * 128 + ((c * 2) ^ ((tv & 7) << 4))) =
        f2bu(acc);
  }
  __syncthreads();   // yT ready; xl DEAD (uA becomes yTG)

  // ---- phase 1b: yTG = y @ G ----
  for (int i = tid; i < 12 * 64; i += 256)
    *(unsigned short*)(yTG + (100 + (i >> 6)) * 128 + ((i & 63) * 2)) = 0;
  for (int idx = tid; idx < 6400; idx += 256) {
    const int c = idx & 63, tv = idx >> 6;
    const int t = tv / 25, v = tv % 25;
    float acc = 0.f;
    #pragma unroll
    for (int u = 0; u < 25; ++u) {
      const int ru = t * 25 + u;
      const float yv = bfu(*(const unsigned short*)((const char*)yT + ru * 128 +
                            ((c * 2) ^ ((ru & 7) << 4))));
      acc = fmaf(yv, Gl[u][v], acc);
    }
    *(unsigned short*)(yTG + tv * 128 + ((c * 2) ^ ((tv & 7) << 4))) =
        f2bu(acc);
  }
  __syncthreads();   // yTG ready — LAST barrier; GEMMs are straight-line

  bf16* qyb = qy  + (size_t)n * 384000 + t0 * 25;
  bf16* kkb = kkp + (size_t)n * 384000 + t0 * 25;
  const float betav = beta[0];

  // ---- q-GEMM ----
  {
    u32x4 aq[2][2];
    LOAD_PFRAGS(aq, wqF);
    for (int nt = 0; nt < 7; ++nt) {
      const int tv = nt * 16 + m16;
      const u32x4 b0 = *(const u32x4*)((const char*)yT + tv * 128 +
                        (((kg * 8) * 2) ^ ((tv & 7) << 4)));
      const u32x4 b1 = *(const u32x4*)((const char*)yT + tv * 128 +
                        (((32 + kg * 8) * 2) ^ ((tv & 7) << 4)));
      #pragma unroll
      for (int mt = 0; mt < 2; ++mt) {
        f32x4 acc = (f32x4)0.f;
        acc = mfma_bf16(aq[mt][0], b0, acc);
        acc = mfma_bf16(aq[mt][1], b1, acc);
        if (tv < 100) {
          const int dr = wid * 32 + mt * 16 + kg * 4;
          #pragma unroll
          for (int i2 = 0; i2 < 4; ++i2)
            qyb[(size_t)(dr + i2) * 3000 + tv] = f2b(acc[i2] + biasb[dr + i2]);
        }
      }
    }
  }

  // ---- k-GEMM into persistent kacc ----
  f32x4 kacc[2][7];
  #pragma unroll
  for (int mt = 0; mt < 2; ++mt)
    #pragma unroll
    for (int nt = 0; nt < 7; ++nt) kacc[mt][nt] = (f32x4)0.f;
  {
    u32x4 ak[2][2];
    LOAD_PFRAGS(ak, wkF);
    for (int nt = 0; nt < 7; ++nt) {
      const int tv = nt * 16 + m16;
      const u32x4 b0 = *(const u32x4*)((const char*)yT + tv * 128 +
                        (((kg * 8) * 2) ^ ((tv & 7) << 4)));
      const u32x4 b1 = *(const u32x4*)((const char*)yT + tv * 128 +
                        (((32 + kg * 8) * 2) ^ ((tv & 7) << 4)));
      #pragma unroll
      for (int mt = 0; mt < 2; ++mt) {
        kacc[mt][nt] = mfma_bf16(ak[mt][0], b0, kacc[mt][nt]);
        kacc[mt][nt] = mfma_bf16(ak[mt][1], b1, kacc[mt][nt]);
      }
    }
  }

  // ---- e-GEMM (beta pre-folded in weF) on yTG, accumulate, store kk ----
  {
    u32x4 ae[2][2];
    LOAD_PFRAGS(ae, weF);
    for (int nt = 0; nt < 7; ++nt) {
      const int tv = nt * 16 + m16;
      const u32x4 b0 = *(const u32x4*)(yTG + tv * 128 +
                        (((kg * 8) * 2) ^ ((tv & 7) << 4)));
      const u32x4 b1 = *(const u32x4*)(yTG + tv * 128 +
                        (((32 + kg * 8) * 2) ^ ((tv & 7) << 4)));
      #pragma unroll
      for (int mt = 0; mt < 2; ++mt) {
        kacc[mt][nt] = mfma_bf16(ae[mt][0], b0, kacc[mt][nt]);
        kacc[mt][nt] = mfma_bf16(ae[mt][1], b1, kacc[mt][nt]);
        if (tv < 100) {
          const int vv = tv % 25;
          const int dr = wid * 32 + mt * 16 + kg * 4;
          #pragma unroll
          for (int i2 = 0; i2 < 4; ++i2)
            kkb[(size_t)(dr + i2) * 3000 + tv] =
                f2b(kacc[mt][nt][i2] + biasb[128 + dr + i2] +
                    betav * biasb[256 + dr + i2] * gsum[vv]);
        }
      }
    }
  }
  #undef LOAD_PFRAGS
  #undef XL
}

// ---------------------------------------------------------------------------
// Kernel C v2 (R16-verbatim, passing): MFMA attention -> padded attP
// ---------------------------------------------------------------------------
__global__ __launch_bounds__(256) void k_att_mfma(
    const bf16* __restrict__ qy, const bf16* __restrict__ kkp,
    const float* __restrict__ bq, const float* __restrict__ disg,
    const float* __restrict__ att0, const float* __restrict__ alpha,
    unsigned short* __restrict__ attP)
{
  const int n = blockIdx.x / HH, h = blockIdx.x % HH;
  __shared__ alignas(16) unsigned short qsA[80][200];  // [u][k] bf16 bits
  __shared__ alignas(16) unsigned short ksB[32][200];  // [v][k] bf16 bits
  __shared__ alignas(16) float att_s[80][28];
  __shared__ float mxv[32], smv[32];
  const int tid = threadIdx.x;
  const int lane = tid & 63, wid = tid >> 6;
  const int m16 = lane & 15, kg = lane >> 4;

  const unsigned short* qyb =
      (const unsigned short*)(qy + ((size_t)(n * DIMD + h * DHD)) * TT * VV);
  const unsigned short* kkb =
      (const unsigned short*)(kkp + ((size_t)(n * DIMD + h * DHD)) * TT * VV);

  f32x4 acc[3];
  #pragma unroll
  for (int s = 0; s < 3; ++s) acc[s] = (f32x4)0.f;

  for (int c = 0; c < 10; ++c) {
    const int t0 = c * TC2;
    __syncthreads();   // prev chunk's frag reads drained
    for (int it = tid; it < 416; it += 256) {
      if (it < 224) {
        const int dh = it / 14, j = it % 14, tq = t0 + j - 1;
        unsigned short vals[25];
        if (tq >= 0 && tq < TT) {
          const unsigned short* src = qyb + ((size_t)dh * TT + tq) * VV;
          #pragma unroll
          for (int u = 0; u < 25; ++u) vals[u] = src[u];
        } else {
          const unsigned short bqv = f2bu(bq[h * DHD + dh]);
          #pragma unroll
          for (int u = 0; u < 25; ++u) vals[u] = bqv;
        }
        #pragma unroll
        for (int w = 0; w < 3; ++w) {
          const int tt = tq - t0 - w + 1;
          if (tt >= 0 && tt < TC2) {
            const int col = tt * 16 + dh;
            #pragma unroll
            for (int u = 0; u < 25; ++u) qsA[w * 25 + u][col] = vals[u];
          }
        }
      } else {
        const int r = it - 224, dh = r / TC2, tt = r % TC2;
        const unsigned short* src = kkb + ((size_t)dh * TT + t0 + tt) * VV;
        const int col = tt * 16 + dh;
        #pragma unroll
        for (int v = 0; v < 25; ++v) ksB[v][col] = src[v];
      }
    }
    __syncthreads();   // tiles ready
    #pragma unroll
    for (int s = 0; s < 3; ++s) {
      const int tidx = wid + 4 * s;
      if (tidx < 10) {
        const int mtile = tidx >> 1, ntile = tidx & 1;
        #pragma unroll
        for (int ks = 0; ks < 6; ++ks) {
          const u32x4 a = *(const u32x4*)&qsA[mtile * 16 + m16][ks * 32 + kg * 8];
          const u32x4 b = *(const u32x4*)&ksB[ntile * 16 + m16][ks * 32 + kg * 8];
          acc[s] = mfma_bf16(a, b, acc[s]);
        }
      }
    }
  }
  __syncthreads();
  #pragma unroll
  for (int s = 0; s < 3; ++s) {
    const int tidx = wid + 4 * s;
    if (tidx < 10) {
      const int mtile = tidx >> 1, ntile = tidx & 1;
      const int v = ntile * 16 + m16;
      if (v < VV) {
        #pragma unroll
        for (int i = 0; i < 4; ++i)
          att_s[mtile * 16 + kg * 4 + i][v] = acc[s][i];
      }
    }
  }
  __syncthreads();
  const float inv = 1.0f / (float)(DHD * TT);
  for (int i = tid; i < UU * VV; i += 256) {
    const int u = i / VV, v = i % VV;
    const bool m = disg[(h * VV + u % VV) * VV + v] > 0.f;
    att_s[u][v] = m ? att_s[u][v] * inv : -9e15f;
  }
  __syncthreads();
  if (tid < VV) {
    float mx = -INFINITY;
    for (int u = 0; u < UU; ++u) mx = fmaxf(mx, att_s[u][tid]);
    float sm = 0.f;
    for (int u = 0; u < UU; ++u) sm += expf(att_s[u][tid] - mx);
    mxv[tid] = mx; smv[tid] = sm;
  }
  __syncthreads();
  const float al = alpha[0];
  unsigned* dst = (unsigned*)(attP + ((size_t)(n * HH + h) * 32) * 104);
  for (int i = tid; i < 1664; i += 256) {     // 32 x 52 u32 (= 104 u16)
    const int vc = i / 52, u0 = (i % 52) * 2;
    unsigned val = 0u;
    if (vc < VV) {
      float f0 = 0.f, f1 = 0.f;
      if (u0 < UU)
        f0 = expf(att_s[u0][vc] - mxv[vc]) / smv[vc] * al
             + att0[(h * VV + u0 % VV) * VV + vc];
      if (u0 + 1 < UU)
        f1 = expf(att_s[u0 + 1][vc] - mxv[vc]) / smv[vc] * al
             + att0[(h * VV + (u0 + 1) % VV) * VV + vc];
      val = pack2(f0, f1);
    }
    dst[i] = val;
  }
}

// ---------------------------------------------------------------------------
// Kernel D v6: a2 frags from pre-packed woF/wdF (coalesced, scales folded).
// ---------------------------------------------------------------------------
__global__ __launch_bounds__(256) void k_out_mfma6(
    const float* __restrict__ x, const unsigned short* __restrict__ attP,
    const unsigned short* __restrict__ woF, const unsigned short* __restrict__ wdF,
    const float* __restrict__ b_o,
    const float* __restrict__ g_o, const float* __restrict__ be_o,
    const float* __restrict__ m_o, const float* __restrict__ v_o,
    const float* __restrict__ b_d,
    const float* __restrict__ g_d, const float* __restrict__ be_d,
    const float* __restrict__ m_d, const float* __restrict__ v_d,
    float* __restrict__ out)
{
  const int n = blockIdx.x / 30, t0 = (blockIdx.x % 30) * TCO;
  __shared__ alignas(16) char uB[28672];                   // xu2 | xsl2[2]
  __shared__ alignas(16) unsigned short attB[2][32][104];  // 13,312 B dbuf
  unsigned short* xu2 = (unsigned short*)uB;               // [(tr*64+c)*104+u]
  const int tid = threadIdx.x;
  const int lane = tid & 63, wid = tid >> 6;
  const int m16 = lane & 15, kg = lane >> 4;

  #define XSLB(b) (uB + (b) * 14336)            // [112] rows x 128B swz

  #define STAGE_XU(tb)                                                         \
    for (int i = tid; i < 2 * 64 * 48; i += 256) {                             \
      const int u0 = (i % 48) * 2, c = (i / 48) & 63, tr = i / (48 * 64);      \
      float f0 = 0.f, f1 = 0.f;                                                \
      if (u0 < UU) {                                                           \
        const int w = u0 / VV, up = u0 % VV, ts = t0 + (tb) + tr + w - 1;      \
        if (ts >= 0 && ts < TT) f0 = x[((n * 64 + c) * TT + ts) * VV + up];    \
      }                                                                        \
      if (u0 + 1 < UU) {                                                       \
        const int u = u0 + 1, w = u / VV, up = u % VV;                         \
        const int ts = t0 + (tb) + tr + w - 1;                                 \
        if (ts >= 0 && ts < TT) f1 = x[((n * 64 + c) * TT + ts) * VV + up];    \
      }                                                                        \
      *(unsigned*)(xu2 + (tr * 64 + c) * 104 + u0) = pack2(f0, f1);            \
    }

  #define STAGE_ATT(hh, buf)                                                   \
    {                                                                          \
      const u32x4* srcv =                                                      \
          (const u32x4*)(attP + ((size_t)(n * HH + (hh)) * 32) * 104);         \
      u32x4* dstv = (u32x4*)&attB[buf][0][0];                                  \
      for (int i = tid; i < 416; i += 256) dstv[i] = srcv[i];                  \
    }

  // ---- prologue: A-frags from xu2 in two 2-t chunks ----
  STAGE_XU(0);
  __syncthreads();
  u32x4 af[4][3];
  if (wid < 2) {
    #pragma unroll
    for (int mt = 0; mt < 4; ++mt)
      #pragma unroll
      for (int ks = 0; ks < 3; ++ks)
        af[mt][ks] = *(const u32x4*)(xu2 + (wid * 64 + mt * 16 + m16) * 104 +
                                     ks * 32 + kg * 8);
  }
  __syncthreads();   // chunk-1 reads drained before overwrite
  STAGE_XU(2);
  STAGE_ATT(0, 0);
  __syncthreads();
  if (wid >= 2) {
    #pragma unroll
    for (int mt = 0; mt < 4; ++mt)
      #pragma unroll
      for (int ks = 0; ks < 3; ++ks)
        af[mt][ks] = *(const u32x4*)(xu2 + ((wid - 2) * 64 + mt * 16 + m16) * 104 +
                                     ks * 32 + kg * 8);
  }
  __syncthreads();   // FENCE: all xu2 reads drained; uB becomes xsl2
  for (int i = tid; i < 2 * 12 * 64; i += 256) {
    const int b = i / (12 * 64), r = i % (12 * 64);
    *(unsigned short*)(XSLB(b) + (100 + (r >> 6)) * 128 + ((r & 63) * 2)) = 0;
  }

  f32x4 acc2[2][7];
  #pragma unroll
  for (int mt = 0; mt < 2; ++mt)
    #pragma unroll
    for (int nt = 0; nt < 7; ++nt) acc2[mt][nt] = (f32x4)0.f;

  for (int h = 0; h <= HH; ++h) {
    const int pb = h & 1;
    char* xs = XSLB(pb);
    // stage2 A-frags from pre-packed tensors (coalesced; scales folded)
    u32x4 a2[2][2];
    #pragma unroll
    for (int mt = 0; mt < 2; ++mt) {
      const int d = wid * 32 + mt * 16 + m16;
      #pragma unroll
      for (int ks = 0; ks < 2; ++ks) {
        const unsigned short* src = (h < HH)
            ? (woF + ((((h * 2 + ks) * 4 + kg) * 128 + d) << 3))
            : (wdF + ((((ks) * 4 + kg) * 128 + d) << 3));
        a2[mt][ks] = *(const u32x4*)src;
      }
    }
    if (h + 1 < HH) { STAGE_ATT(h + 1, (h + 1) & 1); }
    f32x4 a1[4][2];
    if (h < HH) {
      u32x4 bfr[2][3];
      #pragma unroll
      for (int nt = 0; nt < 2; ++nt)
        #pragma unroll
        for (int ks = 0; ks < 3; ++ks)
          bfr[nt][ks] =
              *(const u32x4*)&attB[pb][nt * 16 + m16][ks * 32 + kg * 8];
      #pragma unroll
      for (int mt = 0; mt < 4; ++mt)
        #pragma unroll
        for (int nt = 0; nt < 2; ++nt) {
          a1[mt][nt] = (f32x4)0.f;
          #pragma unroll
          for (int ks = 0; ks < 3; ++ks)
            a1[mt][nt] = mfma_bf16(af[mt][ks], bfr[nt][ks], a1[mt][nt]);
        }
    }
    if (h < HH) {
      #pragma unroll
      for (int mt = 0; mt < 4; ++mt)
        #pragma unroll
        for (int nt = 0; nt < 2; ++nt) {
          const int v = nt * 16 + m16;
          if (v < VV) {
            const int tv = wid * VV + v;
            const int c0 = mt * 16 + kg * 4;
            u32x2 pk;
            pk[0] = pack2(a1[mt][nt][0], a1[mt][nt][1]);
            pk[1] = pack2(a1[mt][nt][2], a1[mt][nt][3]);
            char* p = xs + tv * 128 + ((c0 * 2) ^ ((tv & 7) << 4));
            *(u32x2*)p = pk;
          }
        }
    } else {
      for (int i = tid; i < 6400; i += 256) {
        const int c = i / 100, j = i % 100;
        const float f = x[((size_t)(n * 64 + c) * TT + t0) * VV + j];
        *(unsigned short*)(xs + j * 128 + ((c * 2) ^ ((j & 7) << 4))) =
            f2bu(f);
      }
    }
    __syncthreads();   // single barrier: xs writes(pb) -> reads(pb)
    #pragma unroll
    for (int nt = 0; nt < 7; ++nt) {
      const int tv = nt * 16 + m16;
      const u32x4 b0 = *(const u32x4*)(xs + tv * 128 +
                        (((kg * 8) * 2) ^ ((tv & 7) << 4)));
      const u32x4 b1 = *(const u32x4*)(xs + tv * 128 +
                        (((32 + kg * 8) * 2) ^ ((tv & 7) << 4)));
      #pragma unroll
      for (int mt = 0; mt < 2; ++mt) {
        acc2[mt][nt] = mfma_bf16(a2[mt][0], b0, acc2[mt][nt]);
        acc2[mt][nt] = mfma_bf16(a2[mt][1], b1, acc2[mt][nt]);
      }
    }
  }

  #pragma unroll
  for (int mt = 0; mt < 2; ++mt) {
    float cc[4];
    #pragma unroll
    for (int i = 0; i < 4; ++i) {
      const int d = wid * 32 + mt * 16 + kg * 4 + i;
      const float so2 = g_o[d] * rsqrtf(v_o[d] + 1e-5f);
      const float sd2 = g_d[d] * rsqrtf(v_d[d] + 1e-5f);
      cc[i] = b_o[d] * so2 + be_o[d] - m_o[d] * so2
            + b_d[d] * sd2 + be_d[d] - m_d[d] * sd2;
    }
    #pragma unroll
    for (int nt = 0; nt < 7; ++nt) {
      const int tv = nt * 16 + m16;
      if (tv < 100) {
        const int t = t0 + tv / VV, v = tv % VV;
        #pragma unroll
        for (int i = 0; i < 4; ++i) {
          const int d = wid * 32 + mt * 16 + kg * 4 + i;
          const float z = acc2[mt][nt][i] + cc[i];
          out[((n * DIMD + d) * TT + t) * VV + v] = (z >= 0.f) ? z : 0.1f * z;
        }
      }
    }
  }
  #undef STAGE_XU
  #undef STAGE_ATT
  #undef XSLB
}

// ---------------------------------------------------------------------------
extern "C" void kernel_launch(void* const* d_in, const int* in_sizes, int n_in,
                              void* d_out, int out_size, void* d_ws, size_t ws_size,
                              hipStream_t stream)
{
  (void)in_sizes; (void)n_in; (void)out_size; (void)ws_size;
  const float* x     = (const float*)d_in[0];
  const float* Wq    = (const float*)d_in[1];
  const float* bq    = (const float*)d_in[2];
  const float* Wk    = (const float*)d_in[3];
  const float* bk    = (const float*)d_in[4];
  const float* We    = (const float*)d_in[5];
  const float* be    = (const float*)d_in[6];
  const float* G     = (const float*)d_in[7];
  const float* sepe  = (const float*)d_in[8];
  const float* att0  = (const float*)d_in[9];
  const float* alpha = (const float*)d_in[10];
  const float* beta  = (const float*)d_in[11];
  const float* Wo    = (const float*)d_in[12];
  const float* b_o   = (const float*)d_in[13];
  const float* g_o   = (const float*)d_in[14];
  const float* be_o  = (const float*)d_in[15];
  const float* m_o   = (const float*)d_in[16];
  const float* v_o   = (const float*)d_in[17];
  const float* Wd    = (const float*)d_in[18];
  const float* b_d   = (const float*)d_in[19];
  const float* g_d   = (const float*)d_in[20];
  const float* be_d  = (const float*)d_in[21];
  const float* m_d   = (const float*)d_in[22];
  const float* v_d   = (const float*)d_in[23];
  const int*   dism  = (const int*)d_in[24];
  const float* disg  = (const float*)d_in[25];

  // Workspace: qy @0 (49.152 MB), kk @49,152,000, attP @98,304,000 (3.41 MB),
  // packed weights @101,711,872: woF 131072B, wdF/wqF/wkF/weF 16384B each.
  char* ws = (char*)d_ws;
  bf16* qy   = (bf16*)(ws);
  bf16* kkp  = (bf16*)(ws + 49152000);
  unsigned short* attP = (unsigned short*)(ws + 98304000);
  unsigned short* woF  = (unsigned short*)(ws + 101711872);
  unsigned short* wdF  = (unsigned short*)(ws + 101842944);
  unsigned short* wqF  = (unsigned short*)(ws + 101859328);
  unsigned short* wkF  = (unsigned short*)(ws + 101875712);
  unsigned short* weF  = (unsigned short*)(ws + 101892096);

  k_pack_w<<<384, 256, 0, stream>>>(Wo, g_o, v_o, Wd, g_d, v_d,
                                    Wq, Wk, We, beta,
                                    woF, wdF, wqF, wkF, weF);
  k_qke_mfma7<<<NB * 30, 256, 0, stream>>>(x, wqF, bq, wkF, bk, weF, be,
                                           G, beta, sepe, dism, qy, kkp);
  k_att_mfma<<<NB * HH, 256, 0, stream>>>(qy, kkp, bq, disg, att0, alpha, attP);
  k_out_mfma6<<<NB * 30, 256, 0, stream>>>(x, attP, woF, wdF,
                                           b_o, g_o, be_o, m_o, v_o,
                                           b_d, g_d, be_d, m_d, v_d,
                                           (float*)d_out);
}